// Round 7
// baseline (430.904 us; speedup 1.0000x reference)
//
#include <hip/hip_runtime.h>
#include <hip/hip_bf16.h>
#include <cmath>

#define N_S    2048
#define C_CLS  100
#define K_CL   4
#define A_DIM  128
#define LDSROW 132   // padded row stride: breaks row-power-of-2 bank aliasing
#define NB     16    // GJ panel width
#define MAXPER 96    // max samples per class (mean 20.5; >15 sigma headroom)

// ---------------------------------------------------------------------------
// Kernel 0: bucket samples by class
// ---------------------------------------------------------------------------
__global__ __launch_bounds__(256) void k_bucket(
    const int* __restrict__ labels, int* __restrict__ cntg, int* __restrict__ idxg)
{
    __shared__ int cntL[C_CLS];
    const int t = threadIdx.x;
    if (t < C_CLS) cntL[t] = 0;
    __syncthreads();
    for (int n = t; n < N_S; n += 256) {
        int c = labels[n];
        int slot = atomicAdd(&cntL[c], 1);
        if (slot < MAXPER) idxg[c * MAXPER + slot] = n;
    }
    __syncthreads();
    if (t < C_CLS) cntg[t] = min(cntL[t], MAXPER);
}

// ---------------------------------------------------------------------------
// Kernel 1: blocked GJ inverse of sigma[cl,k] in LDS + fused logdet + per-
// sample quadratic form. Round-6 lesson: scratch traffic tracks the FULLY
// UNROLLED independent-load k-loops (compiler hoists 16-32 ds_read_b128
// results -> >128 live VGPRs -> spill), not named arrays. Fix: partial
// unroll (4) keeps <=4 loads in flight; launch_bounds(512,4) caps VGPR at
// 128 and allows 2 blocks/CU (LDS 75.5KB*2 <= 160KB).
// ---------------------------------------------------------------------------
__global__ __launch_bounds__(512, 4) void k_invert_score(
    const float* __restrict__ sigma, const float* __restrict__ mu,
    const float* __restrict__ features, const int* __restrict__ cntg,
    const int* __restrict__ idxg, float* __restrict__ score)
{
    __shared__ __align__(16) float As[A_DIM * LDSROW];   // 67.6 KB
    __shared__ __align__(16) float Rbuf[NB * A_DIM];     // 8.2 KB
    __shared__ float DinvS[NB * 17];                     // conflict-free rows
    __shared__ float ldS;

    const int tid  = threadIdx.x;
    const int bid  = blockIdx.x;        // cl*K_CL + k
    const int cl   = bid >> 2;
    const int lane = tid & 63;
    const int wv   = tid >> 6;

    // ---- stage sigma (coalesced b128) ----
    const float4* src = (const float4*)(sigma + (size_t)bid * A_DIM * A_DIM);
    for (int e4 = tid; e4 < A_DIM * 32; e4 += 512) {
        int i = e4 >> 5, j4 = e4 & 31;
        *(float4*)&As[i * LDSROW + 4 * j4] = src[e4];
    }
    __syncthreads();

    float logdet = 0.0f;                 // valid in wave 0 only

    for (int t = 0; t < 8; ++t) {
        const int p0 = NB * t;

        // (a) wave 0: invert 16x16 diagonal block in registers (shfl GJ)
        if (wv == 0) {
            const int r = lane >> 2, cg = lane & 3;
            float4 dv = *(const float4*)&As[(p0 + r) * LDSROW + p0 + 4 * cg];
            #pragma unroll
            for (int p = 0; p < NB; ++p) {
                const int sel = p & 3, pr4 = p >> 2;
                float te = (sel == 0) ? dv.x : (sel == 1) ? dv.y : (sel == 2) ? dv.z : dv.w;
                float piv = __shfl(te, (p << 2) | pr4, 64);
                float ip  = 1.0f / piv;
                logdet += __logf(piv);
                const int rowsrc = (p << 2) | cg;
                float4 prs;
                prs.x = __shfl(dv.x, rowsrc, 64) * ip;
                prs.y = __shfl(dv.y, rowsrc, 64) * ip;
                prs.z = __shfl(dv.z, rowsrc, 64) * ip;
                prs.w = __shfl(dv.w, rowsrc, 64) * ip;
                if (cg == pr4) (&prs.x)[sel] = ip;           // (p,p) -> 1/piv
                float f = __shfl(te, (lane & ~3) | pr4, 64); // my row's col-p value
                if (r == p) {
                    dv = prs;
                } else {
                    dv.x -= f * prs.x; dv.y -= f * prs.y;
                    dv.z -= f * prs.z; dv.w -= f * prs.w;
                    if (cg == pr4) (&dv.x)[sel] = -f * ip;   // col p: assign
                }
            }
            DinvS[r * 17 + 4 * cg + 0] = dv.x;
            DinvS[r * 17 + 4 * cg + 1] = dv.y;
            DinvS[r * 17 + 4 * cg + 2] = dv.z;
            DinvS[r * 17 + 4 * cg + 3] = dv.w;
        }
        __syncthreads();   // b1: Dinv ready

        // (b) Rnew = Dinv * A[P,:] into Rbuf; panel cols get Dinv itself.
        // 512 threads: one float4 each. unroll 4: <=4 loads in flight.
        {
            const int rr = tid >> 5, j4c = tid & 31;
            float4 o;
            if ((j4c >> 2) == t) {
                const int cg = j4c & 3;
                o.x = DinvS[rr * 17 + 4 * cg + 0];
                o.y = DinvS[rr * 17 + 4 * cg + 1];
                o.z = DinvS[rr * 17 + 4 * cg + 2];
                o.w = DinvS[rr * 17 + 4 * cg + 3];
            } else {
                o.x = 0.f; o.y = 0.f; o.z = 0.f; o.w = 0.f;
                #pragma unroll 4
                for (int k = 0; k < NB; ++k) {
                    const float a = DinvS[rr * 17 + k];          // broadcast
                    const float4 s4 = *(const float4*)&As[(p0 + k) * LDSROW + 4 * j4c];
                    o.x += a * s4.x; o.y += a * s4.y; o.z += a * s4.z; o.w += a * s4.w;
                }
            }
            *(float4*)&Rbuf[rr * A_DIM + 4 * j4c] = o;
        }
        __syncthreads();   // b2: Rnew ready (As panel rows still OLD)

        // (c) rank-16 update of 112 non-panel rows: per thread 4 rows x 8 cols.
        // cold read on-the-fly (LDS broadcast); unroll 4 caps load hoisting.
        if (tid < 448) {
            const int rgi = tid >> 4;                 // 0..27 non-panel row group
            const int cp  = tid & 15;                 // j4 pair
            const int rga = (rgi < 4 * t) ? rgi : rgi + 4;
            const int row0 = 4 * rga;
            const int c0 = 8 * cp, c1 = 8 * cp + 4;
            const bool pcol = ((cp >> 1) == t);       // my 2 j4s are the panel cols
            float4 a00, a01, a10, a11, a20, a21, a30, a31;
            if (pcol) {
                a00 = a01 = a10 = a11 = a20 = a21 = a30 = a31 = (float4){0, 0, 0, 0};
            } else {
                a00 = *(const float4*)&As[(row0 + 0) * LDSROW + c0];
                a01 = *(const float4*)&As[(row0 + 0) * LDSROW + c1];
                a10 = *(const float4*)&As[(row0 + 1) * LDSROW + c0];
                a11 = *(const float4*)&As[(row0 + 1) * LDSROW + c1];
                a20 = *(const float4*)&As[(row0 + 2) * LDSROW + c0];
                a21 = *(const float4*)&As[(row0 + 2) * LDSROW + c1];
                a30 = *(const float4*)&As[(row0 + 3) * LDSROW + c0];
                a31 = *(const float4*)&As[(row0 + 3) * LDSROW + c1];
            }
            #pragma unroll 4
            for (int k = 0; k < NB; ++k) {
                const float4 r0 = *(const float4*)&Rbuf[k * A_DIM + c0];
                const float4 r1 = *(const float4*)&Rbuf[k * A_DIM + c1];
                const float f0 = As[(row0 + 0) * LDSROW + p0 + k];
                const float f1 = As[(row0 + 1) * LDSROW + p0 + k];
                const float f2 = As[(row0 + 2) * LDSROW + p0 + k];
                const float f3 = As[(row0 + 3) * LDSROW + p0 + k];
                a00.x -= f0 * r0.x; a00.y -= f0 * r0.y; a00.z -= f0 * r0.z; a00.w -= f0 * r0.w;
                a01.x -= f0 * r1.x; a01.y -= f0 * r1.y; a01.z -= f0 * r1.z; a01.w -= f0 * r1.w;
                a10.x -= f1 * r0.x; a10.y -= f1 * r0.y; a10.z -= f1 * r0.z; a10.w -= f1 * r0.w;
                a11.x -= f1 * r1.x; a11.y -= f1 * r1.y; a11.z -= f1 * r1.z; a11.w -= f1 * r1.w;
                a20.x -= f2 * r0.x; a20.y -= f2 * r0.y; a20.z -= f2 * r0.z; a20.w -= f2 * r0.w;
                a21.x -= f2 * r1.x; a21.y -= f2 * r1.y; a21.z -= f2 * r1.z; a21.w -= f2 * r1.w;
                a30.x -= f3 * r0.x; a30.y -= f3 * r0.y; a30.z -= f3 * r0.z; a30.w -= f3 * r0.w;
                a31.x -= f3 * r1.x; a31.y -= f3 * r1.y; a31.z -= f3 * r1.z; a31.w -= f3 * r1.w;
            }
            *(float4*)&As[(row0 + 0) * LDSROW + c0] = a00;
            *(float4*)&As[(row0 + 0) * LDSROW + c1] = a01;
            *(float4*)&As[(row0 + 1) * LDSROW + c0] = a10;
            *(float4*)&As[(row0 + 1) * LDSROW + c1] = a11;
            *(float4*)&As[(row0 + 2) * LDSROW + c0] = a20;
            *(float4*)&As[(row0 + 2) * LDSROW + c1] = a21;
            *(float4*)&As[(row0 + 3) * LDSROW + c0] = a30;
            *(float4*)&As[(row0 + 3) * LDSROW + c1] = a31;
        }
        // copyback Rbuf -> As panel rows (panel rows untouched by the update)
        {
            const int rr = tid >> 5, j4c = tid & 31;
            *(float4*)&As[(p0 + rr) * LDSROW + 4 * j4c] =
                *(const float4*)&Rbuf[rr * A_DIM + 4 * j4c];
        }
        __syncthreads();   // b3: panel done
    }
    // As = Sigma^{-1}

    if (tid == 0) ldS = logdet;
    __syncthreads();
    const float ld = ldS;

    // ---- per-sample quadratic form (bucketed; one sample per wave) ----
    const float m0 = mu[(size_t)bid * A_DIM + lane];
    const float m1 = mu[(size_t)bid * A_DIM + 64 + lane];
    const int cnt = cntg[cl];
    for (int s = wv; s < cnt; s += 8) {
        const int n = idxg[cl * MAXPER + s];
        float d0 = features[(size_t)n * A_DIM + lane]      - m0;
        float d1 = features[(size_t)n * A_DIM + 64 + lane] - m1;
        float p0v = 0.f, p1v = 0.f;
        for (int i = 0; i < 64; ++i) {
            float b = __shfl(d0, i, 64);
            p0v += b * As[i * LDSROW + lane];
            p1v += b * As[i * LDSROW + 64 + lane];
        }
        for (int i = 0; i < 64; ++i) {
            float b = __shfl(d1, i, 64);
            p0v += b * As[(i + 64) * LDSROW + lane];
            p1v += b * As[(i + 64) * LDSROW + 64 + lane];
        }
        float q = d0 * p0v + d1 * p1v;
        #pragma unroll
        for (int off = 32; off; off >>= 1) q += __shfl_xor(q, off, 64);
        if (lane == 0) score[n * K_CL + (bid & 3)] = q + ld;
    }
}

// ---------------------------------------------------------------------------
// Kernel 2: per (cl,k): gdiag[c]=W[c] S W[c]^T, gcol[c]=W[c] S W[cl]^T
// (named scalar accumulators; LDS-broadcast W reads; unchanged)
// ---------------------------------------------------------------------------
__global__ __launch_bounds__(256) void k_gprep(
    const float* __restrict__ sigma, const float* __restrict__ weight,
    float* __restrict__ gdiag, float* __restrict__ gcol)
{
    __shared__ __align__(16) float Ss[A_DIM * A_DIM];   // 64 KB
    __shared__ __align__(16) float Ws[C_CLS * A_DIM];   // 51.2 KB
    const int tid = threadIdx.x, bid = blockIdx.x;
    const int cl  = bid >> 2;
    const int lane = tid & 63, wv = tid >> 6;

    const float4* src = (const float4*)(sigma + (size_t)bid * A_DIM * A_DIM);
    for (int e4 = tid; e4 < A_DIM * 32; e4 += 256)
        ((float4*)Ss)[e4] = src[e4];
    const float4* wsrc = (const float4*)weight;
    for (int e4 = tid; e4 < C_CLS * 32; e4 += 256)
        ((float4*)Ws)[e4] = wsrc[e4];
    __syncthreads();

    const float wc0 = Ws[cl * A_DIM + lane];
    const float wc1 = Ws[cl * A_DIM + 64 + lane];
    const int cbeg = wv * 25;               // 4 waves x 25 classes = 100

    for (int g = 0; g < 5; ++g) {           // 5 uniform groups of 5 rows
        const int c0 = cbeg + g * 5;
        const float* w0 = &Ws[(c0 + 0) * A_DIM];
        const float* w1 = &Ws[(c0 + 1) * A_DIM];
        const float* w2 = &Ws[(c0 + 2) * A_DIM];
        const float* w3 = &Ws[(c0 + 3) * A_DIM];
        const float* w4 = &Ws[(c0 + 4) * A_DIM];
        float h00 = 0.f, h01 = 0.f, h02 = 0.f, h03 = 0.f, h04 = 0.f;  // j = lane
        float h10 = 0.f, h11 = 0.f, h12 = 0.f, h13 = 0.f, h14 = 0.f;  // j = lane+64
        #pragma unroll 4
        for (int i = 0; i < A_DIM; ++i) {
            const float s0 = Ss[i * A_DIM + lane];
            const float s1 = Ss[i * A_DIM + 64 + lane];
            const float b0 = w0[i], b1 = w1[i], b2 = w2[i], b3 = w3[i], b4 = w4[i];
            h00 += b0 * s0; h10 += b0 * s1;
            h01 += b1 * s0; h11 += b1 * s1;
            h02 += b2 * s0; h12 += b2 * s1;
            h03 += b3 * s0; h13 += b3 * s1;
            h04 += b4 * s0; h14 += b4 * s1;
        }
        #define GOUT(HA, HB, CC)                                            \
        {                                                                   \
            const int c = c0 + (CC);                                        \
            float pd = (HA) * Ws[c * A_DIM + lane]                          \
                     + (HB) * Ws[c * A_DIM + 64 + lane];                    \
            float pc = (HA) * wc0 + (HB) * wc1;                             \
            _Pragma("unroll")                                               \
            for (int off = 32; off; off >>= 1) {                            \
                pd += __shfl_xor(pd, off, 64);                              \
                pc += __shfl_xor(pc, off, 64);                              \
            }                                                               \
            if (lane == 0) {                                                \
                gdiag[bid * C_CLS + c] = pd;                                \
                gcol [bid * C_CLS + c] = pc;                                \
            }                                                               \
        }
        GOUT(h00, h10, 0)
        GOUT(h01, h11, 1)
        GOUT(h02, h12, 2)
        GOUT(h03, h13, 3)
        GOUT(h04, h14, 4)
        #undef GOUT
    }
}

// ---------------------------------------------------------------------------
// Kernel 3 (fused fc + final)
// ---------------------------------------------------------------------------
__global__ __launch_bounds__(128) void k_out(
    const float* __restrict__ features, const float* __restrict__ weight,
    const float* __restrict__ bias, const int* __restrict__ labels,
    const float* __restrict__ score, const float* __restrict__ gdiag,
    const float* __restrict__ gcol, const float* __restrict__ ratio_p,
    float* __restrict__ y, float* __restrict__ loss)
{
    __shared__ __align__(16) float xs[A_DIM];
    __shared__ float red[2], red2[2], acl_s;
    const int n = blockIdx.x, t = threadIdx.x;
    xs[t] = features[(size_t)n * A_DIM + t];
    __syncthreads();

    const int cl = labels[n];
    const float ratio = *ratio_p;

    float s0 = score[n * 4 + 0], s1 = score[n * 4 + 1];
    float s2 = score[n * 4 + 2], s3 = score[n * 4 + 3];
    int ks = 0; float bs = s0;                   // strict <: first-min == jnp first-max
    if (s1 < bs) { bs = s1; ks = 1; }
    if (s2 < bs) { bs = s2; ks = 2; }
    if (s3 < bs) { bs = s3; ks = 3; }

    const int base = (cl * 4 + ks) * C_CLS;
    const float gll = gdiag[base + cl];
    float aug = -INFINITY;
    if (t < C_CLS) {
        const float4* wr = (const float4*)(weight + t * A_DIM);
        const float4* xr = (const float4*)xs;
        float acc = bias[t];
        #pragma unroll
        for (int j = 0; j < 32; ++j) {
            float4 a = xr[j], b = wr[j];
            acc += a.x * b.x + a.y * b.y + a.z * b.z + a.w * b.w;
        }
        y[(size_t)n * C_CLS + t] = acc;
        aug = acc + 0.5f * ratio * (gdiag[base + t] - 2.0f * gcol[base + t] + gll);
    }

    float m = aug;
    #pragma unroll
    for (int off = 32; off; off >>= 1) m = fmaxf(m, __shfl_xor(m, off, 64));
    if ((t & 63) == 0) red[t >> 6] = m;
    __syncthreads();
    m = fmaxf(red[0], red[1]);

    float e = (t < C_CLS) ? expf(aug - m) : 0.0f;
    #pragma unroll
    for (int off = 32; off; off >>= 1) e += __shfl_xor(e, off, 64);
    if ((t & 63) == 0) red2[t >> 6] = e;
    if (t == cl) acl_s = aug;
    __syncthreads();

    if (t == 0) {
        float sum = red2[0] + red2[1];
        float lp = acl_s - m - logf(sum);
        atomicAdd(loss, -lp * (1.0f / (float)N_S));
    }
}

// ---------------------------------------------------------------------------
extern "C" void kernel_launch(void* const* d_in, const int* in_sizes, int n_in,
                              void* d_out, int out_size, void* d_ws, size_t ws_size,
                              hipStream_t stream) {
    const float* features = (const float*)d_in[0];
    const float* weight   = (const float*)d_in[1];
    const float* bias     = (const float*)d_in[2];
    // d_in[3] = pi : unused (q is one-hot for any pi > 0; argmax unaffected)
    const float* mu       = (const float*)d_in[4];
    const float* sigma    = (const float*)d_in[5];
    const int*   labels   = (const int*)d_in[6];
    const float* ratio    = (const float*)d_in[7];

    float* out   = (float*)d_out;   // [0] = loss, [1..204800] = y
    float* yout  = out + 1;
    float* score = (float*)d_ws;                  // 8192 f32
    float* gdiag = score + N_S * K_CL;            // 40000 f32
    float* gcol  = gdiag + C_CLS * K_CL * C_CLS;  // 40000 f32
    int*   cntg  = (int*)(gcol + C_CLS * K_CL * C_CLS);  // 100 int
    int*   idxg  = cntg + C_CLS;                          // 100*96 int

    hipMemsetAsync(d_out, 0, sizeof(float), stream);   // zero the loss accumulator

    k_bucket      <<<dim3(1),            dim3(256), 0, stream>>>(labels, cntg, idxg);
    k_invert_score<<<dim3(C_CLS * K_CL), dim3(512), 0, stream>>>(sigma, mu, features, cntg, idxg, score);
    k_gprep       <<<dim3(C_CLS * K_CL), dim3(256), 0, stream>>>(sigma, weight, gdiag, gcol);
    k_out         <<<dim3(N_S),          dim3(128), 0, stream>>>(features, weight, bias, labels,
                                                                 score, gdiag, gcol, ratio, yout, out);
}

// Round 8
// 353.762 us; speedup vs baseline: 1.2181x; 1.2181x over previous
//
#include <hip/hip_runtime.h>
#include <hip/hip_bf16.h>
#include <cmath>

#define N_S    2048
#define C_CLS  100
#define K_CL   4
#define A_DIM  128
#define LDSROW 132   // padded row stride: breaks row-power-of-2 bank aliasing
#define NB     16    // GJ panel width
#define MAXPER 96    // max samples per class (mean 20.5; >15 sigma headroom)

// ---------------------------------------------------------------------------
// Kernel 0: bucket samples by class
// ---------------------------------------------------------------------------
__global__ __launch_bounds__(256) void k_bucket(
    const int* __restrict__ labels, int* __restrict__ cntg, int* __restrict__ idxg)
{
    __shared__ int cntL[C_CLS];
    const int t = threadIdx.x;
    if (t < C_CLS) cntL[t] = 0;
    __syncthreads();
    for (int n = t; n < N_S; n += 256) {
        int c = labels[n];
        int slot = atomicAdd(&cntL[c], 1);
        if (slot < MAXPER) idxg[c * MAXPER + slot] = n;
    }
    __syncthreads();
    if (t < C_CLS) cntg[t] = min(cntL[t], MAXPER);
}

// ---------------------------------------------------------------------------
// Kernel 1: blocked GJ inverse of sigma[cl,k] in LDS + fused logdet + per-
// sample quadratic form.
// Round-7 lesson: (512,4) made the allocator halve VGPR to 64 -> MORE spill.
// Revert to (512,2) (measured 128 VGPR in round 6); keep ONLY unroll-4 on the
// two k-loops so <=4 load groups are in flight (~90 live VGPR < 128).
// ---------------------------------------------------------------------------
__global__ __launch_bounds__(512, 2) void k_invert_score(
    const float* __restrict__ sigma, const float* __restrict__ mu,
    const float* __restrict__ features, const int* __restrict__ cntg,
    const int* __restrict__ idxg, float* __restrict__ score)
{
    __shared__ __align__(16) float As[A_DIM * LDSROW];   // 67.6 KB
    __shared__ __align__(16) float Rbuf[NB * A_DIM];     // 8.2 KB
    __shared__ float DinvS[NB * 17];                     // conflict-free rows
    __shared__ float ldS;

    const int tid  = threadIdx.x;
    const int bid  = blockIdx.x;        // cl*K_CL + k
    const int cl   = bid >> 2;
    const int lane = tid & 63;
    const int wv   = tid >> 6;

    // ---- stage sigma (coalesced b128) ----
    const float4* src = (const float4*)(sigma + (size_t)bid * A_DIM * A_DIM);
    for (int e4 = tid; e4 < A_DIM * 32; e4 += 512) {
        int i = e4 >> 5, j4 = e4 & 31;
        *(float4*)&As[i * LDSROW + 4 * j4] = src[e4];
    }
    __syncthreads();

    float logdet = 0.0f;                 // valid in wave 0 only

    for (int t = 0; t < 8; ++t) {
        const int p0 = NB * t;

        // (a) wave 0: invert 16x16 diagonal block in registers (shfl GJ)
        if (wv == 0) {
            const int r = lane >> 2, cg = lane & 3;
            float4 dv = *(const float4*)&As[(p0 + r) * LDSROW + p0 + 4 * cg];
            #pragma unroll
            for (int p = 0; p < NB; ++p) {
                const int sel = p & 3, pr4 = p >> 2;
                float te = (sel == 0) ? dv.x : (sel == 1) ? dv.y : (sel == 2) ? dv.z : dv.w;
                float piv = __shfl(te, (p << 2) | pr4, 64);
                float ip  = 1.0f / piv;
                logdet += __logf(piv);
                const int rowsrc = (p << 2) | cg;
                float4 prs;
                prs.x = __shfl(dv.x, rowsrc, 64) * ip;
                prs.y = __shfl(dv.y, rowsrc, 64) * ip;
                prs.z = __shfl(dv.z, rowsrc, 64) * ip;
                prs.w = __shfl(dv.w, rowsrc, 64) * ip;
                if (cg == pr4) (&prs.x)[sel] = ip;           // (p,p) -> 1/piv
                float f = __shfl(te, (lane & ~3) | pr4, 64); // my row's col-p value
                if (r == p) {
                    dv = prs;
                } else {
                    dv.x -= f * prs.x; dv.y -= f * prs.y;
                    dv.z -= f * prs.z; dv.w -= f * prs.w;
                    if (cg == pr4) (&dv.x)[sel] = -f * ip;   // col p: assign
                }
            }
            DinvS[r * 17 + 4 * cg + 0] = dv.x;
            DinvS[r * 17 + 4 * cg + 1] = dv.y;
            DinvS[r * 17 + 4 * cg + 2] = dv.z;
            DinvS[r * 17 + 4 * cg + 3] = dv.w;
        }
        __syncthreads();   // b1: Dinv ready

        // (b) Rnew = Dinv * A[P,:] into Rbuf; panel cols get Dinv itself.
        // 512 threads: one float4 each. unroll 4: <=4 loads in flight.
        {
            const int rr = tid >> 5, j4c = tid & 31;
            float4 o;
            if ((j4c >> 2) == t) {
                const int cg = j4c & 3;
                o.x = DinvS[rr * 17 + 4 * cg + 0];
                o.y = DinvS[rr * 17 + 4 * cg + 1];
                o.z = DinvS[rr * 17 + 4 * cg + 2];
                o.w = DinvS[rr * 17 + 4 * cg + 3];
            } else {
                o.x = 0.f; o.y = 0.f; o.z = 0.f; o.w = 0.f;
                #pragma unroll 4
                for (int k = 0; k < NB; ++k) {
                    const float a = DinvS[rr * 17 + k];          // broadcast
                    const float4 s4 = *(const float4*)&As[(p0 + k) * LDSROW + 4 * j4c];
                    o.x += a * s4.x; o.y += a * s4.y; o.z += a * s4.z; o.w += a * s4.w;
                }
            }
            *(float4*)&Rbuf[rr * A_DIM + 4 * j4c] = o;
        }
        __syncthreads();   // b2: Rnew ready (As panel rows still OLD)

        // (c) rank-16 update of 112 non-panel rows: per thread 4 rows x 8 cols.
        // cold read on-the-fly (LDS broadcast); unroll 4 caps load hoisting.
        if (tid < 448) {
            const int rgi = tid >> 4;                 // 0..27 non-panel row group
            const int cp  = tid & 15;                 // j4 pair
            const int rga = (rgi < 4 * t) ? rgi : rgi + 4;
            const int row0 = 4 * rga;
            const int c0 = 8 * cp, c1 = 8 * cp + 4;
            const bool pcol = ((cp >> 1) == t);       // my 2 j4s are the panel cols
            float4 a00, a01, a10, a11, a20, a21, a30, a31;
            if (pcol) {
                a00 = a01 = a10 = a11 = a20 = a21 = a30 = a31 = (float4){0, 0, 0, 0};
            } else {
                a00 = *(const float4*)&As[(row0 + 0) * LDSROW + c0];
                a01 = *(const float4*)&As[(row0 + 0) * LDSROW + c1];
                a10 = *(const float4*)&As[(row0 + 1) * LDSROW + c0];
                a11 = *(const float4*)&As[(row0 + 1) * LDSROW + c1];
                a20 = *(const float4*)&As[(row0 + 2) * LDSROW + c0];
                a21 = *(const float4*)&As[(row0 + 2) * LDSROW + c1];
                a30 = *(const float4*)&As[(row0 + 3) * LDSROW + c0];
                a31 = *(const float4*)&As[(row0 + 3) * LDSROW + c1];
            }
            #pragma unroll 4
            for (int k = 0; k < NB; ++k) {
                const float4 r0 = *(const float4*)&Rbuf[k * A_DIM + c0];
                const float4 r1 = *(const float4*)&Rbuf[k * A_DIM + c1];
                const float f0 = As[(row0 + 0) * LDSROW + p0 + k];
                const float f1 = As[(row0 + 1) * LDSROW + p0 + k];
                const float f2 = As[(row0 + 2) * LDSROW + p0 + k];
                const float f3 = As[(row0 + 3) * LDSROW + p0 + k];
                a00.x -= f0 * r0.x; a00.y -= f0 * r0.y; a00.z -= f0 * r0.z; a00.w -= f0 * r0.w;
                a01.x -= f0 * r1.x; a01.y -= f0 * r1.y; a01.z -= f0 * r1.z; a01.w -= f0 * r1.w;
                a10.x -= f1 * r0.x; a10.y -= f1 * r0.y; a10.z -= f1 * r0.z; a10.w -= f1 * r0.w;
                a11.x -= f1 * r1.x; a11.y -= f1 * r1.y; a11.z -= f1 * r1.z; a11.w -= f1 * r1.w;
                a20.x -= f2 * r0.x; a20.y -= f2 * r0.y; a20.z -= f2 * r0.z; a20.w -= f2 * r0.w;
                a21.x -= f2 * r1.x; a21.y -= f2 * r1.y; a21.z -= f2 * r1.z; a21.w -= f2 * r1.w;
                a30.x -= f3 * r0.x; a30.y -= f3 * r0.y; a30.z -= f3 * r0.z; a30.w -= f3 * r0.w;
                a31.x -= f3 * r1.x; a31.y -= f3 * r1.y; a31.z -= f3 * r1.z; a31.w -= f3 * r1.w;
            }
            *(float4*)&As[(row0 + 0) * LDSROW + c0] = a00;
            *(float4*)&As[(row0 + 0) * LDSROW + c1] = a01;
            *(float4*)&As[(row0 + 1) * LDSROW + c0] = a10;
            *(float4*)&As[(row0 + 1) * LDSROW + c1] = a11;
            *(float4*)&As[(row0 + 2) * LDSROW + c0] = a20;
            *(float4*)&As[(row0 + 2) * LDSROW + c1] = a21;
            *(float4*)&As[(row0 + 3) * LDSROW + c0] = a30;
            *(float4*)&As[(row0 + 3) * LDSROW + c1] = a31;
        }
        // copyback Rbuf -> As panel rows (panel rows untouched by the update)
        {
            const int rr = tid >> 5, j4c = tid & 31;
            *(float4*)&As[(p0 + rr) * LDSROW + 4 * j4c] =
                *(const float4*)&Rbuf[rr * A_DIM + 4 * j4c];
        }
        __syncthreads();   // b3: panel done
    }
    // As = Sigma^{-1}

    if (tid == 0) ldS = logdet;
    __syncthreads();
    const float ld = ldS;

    // ---- per-sample quadratic form (bucketed; one sample per wave) ----
    const float m0 = mu[(size_t)bid * A_DIM + lane];
    const float m1 = mu[(size_t)bid * A_DIM + 64 + lane];
    const int cnt = cntg[cl];
    for (int s = wv; s < cnt; s += 8) {
        const int n = idxg[cl * MAXPER + s];
        float d0 = features[(size_t)n * A_DIM + lane]      - m0;
        float d1 = features[(size_t)n * A_DIM + 64 + lane] - m1;
        float p0v = 0.f, p1v = 0.f;
        for (int i = 0; i < 64; ++i) {
            float b = __shfl(d0, i, 64);
            p0v += b * As[i * LDSROW + lane];
            p1v += b * As[i * LDSROW + 64 + lane];
        }
        for (int i = 0; i < 64; ++i) {
            float b = __shfl(d1, i, 64);
            p0v += b * As[(i + 64) * LDSROW + lane];
            p1v += b * As[(i + 64) * LDSROW + 64 + lane];
        }
        float q = d0 * p0v + d1 * p1v;
        #pragma unroll
        for (int off = 32; off; off >>= 1) q += __shfl_xor(q, off, 64);
        if (lane == 0) score[n * K_CL + (bid & 3)] = q + ld;
    }
}

// ---------------------------------------------------------------------------
// Kernel 2: per (cl,k): gdiag[c]=W[c] S W[c]^T, gcol[c]=W[c] S W[cl]^T
// (named scalar accumulators; LDS-broadcast W reads; unchanged)
// ---------------------------------------------------------------------------
__global__ __launch_bounds__(256) void k_gprep(
    const float* __restrict__ sigma, const float* __restrict__ weight,
    float* __restrict__ gdiag, float* __restrict__ gcol)
{
    __shared__ __align__(16) float Ss[A_DIM * A_DIM];   // 64 KB
    __shared__ __align__(16) float Ws[C_CLS * A_DIM];   // 51.2 KB
    const int tid = threadIdx.x, bid = blockIdx.x;
    const int cl  = bid >> 2;
    const int lane = tid & 63, wv = tid >> 6;

    const float4* src = (const float4*)(sigma + (size_t)bid * A_DIM * A_DIM);
    for (int e4 = tid; e4 < A_DIM * 32; e4 += 256)
        ((float4*)Ss)[e4] = src[e4];
    const float4* wsrc = (const float4*)weight;
    for (int e4 = tid; e4 < C_CLS * 32; e4 += 256)
        ((float4*)Ws)[e4] = wsrc[e4];
    __syncthreads();

    const float wc0 = Ws[cl * A_DIM + lane];
    const float wc1 = Ws[cl * A_DIM + 64 + lane];
    const int cbeg = wv * 25;               // 4 waves x 25 classes = 100

    for (int g = 0; g < 5; ++g) {           // 5 uniform groups of 5 rows
        const int c0 = cbeg + g * 5;
        const float* w0 = &Ws[(c0 + 0) * A_DIM];
        const float* w1 = &Ws[(c0 + 1) * A_DIM];
        const float* w2 = &Ws[(c0 + 2) * A_DIM];
        const float* w3 = &Ws[(c0 + 3) * A_DIM];
        const float* w4 = &Ws[(c0 + 4) * A_DIM];
        float h00 = 0.f, h01 = 0.f, h02 = 0.f, h03 = 0.f, h04 = 0.f;  // j = lane
        float h10 = 0.f, h11 = 0.f, h12 = 0.f, h13 = 0.f, h14 = 0.f;  // j = lane+64
        #pragma unroll 4
        for (int i = 0; i < A_DIM; ++i) {
            const float s0 = Ss[i * A_DIM + lane];
            const float s1 = Ss[i * A_DIM + 64 + lane];
            const float b0 = w0[i], b1 = w1[i], b2 = w2[i], b3 = w3[i], b4 = w4[i];
            h00 += b0 * s0; h10 += b0 * s1;
            h01 += b1 * s0; h11 += b1 * s1;
            h02 += b2 * s0; h12 += b2 * s1;
            h03 += b3 * s0; h13 += b3 * s1;
            h04 += b4 * s0; h14 += b4 * s1;
        }
        #define GOUT(HA, HB, CC)                                            \
        {                                                                   \
            const int c = c0 + (CC);                                        \
            float pd = (HA) * Ws[c * A_DIM + lane]                          \
                     + (HB) * Ws[c * A_DIM + 64 + lane];                    \
            float pc = (HA) * wc0 + (HB) * wc1;                             \
            _Pragma("unroll")                                               \
            for (int off = 32; off; off >>= 1) {                            \
                pd += __shfl_xor(pd, off, 64);                              \
                pc += __shfl_xor(pc, off, 64);                              \
            }                                                               \
            if (lane == 0) {                                                \
                gdiag[bid * C_CLS + c] = pd;                                \
                gcol [bid * C_CLS + c] = pc;                                \
            }                                                               \
        }
        GOUT(h00, h10, 0)
        GOUT(h01, h11, 1)
        GOUT(h02, h12, 2)
        GOUT(h03, h13, 3)
        GOUT(h04, h14, 4)
        #undef GOUT
    }
}

// ---------------------------------------------------------------------------
// Kernel 3 (fused fc + final)
// ---------------------------------------------------------------------------
__global__ __launch_bounds__(128) void k_out(
    const float* __restrict__ features, const float* __restrict__ weight,
    const float* __restrict__ bias, const int* __restrict__ labels,
    const float* __restrict__ score, const float* __restrict__ gdiag,
    const float* __restrict__ gcol, const float* __restrict__ ratio_p,
    float* __restrict__ y, float* __restrict__ loss)
{
    __shared__ __align__(16) float xs[A_DIM];
    __shared__ float red[2], red2[2], acl_s;
    const int n = blockIdx.x, t = threadIdx.x;
    xs[t] = features[(size_t)n * A_DIM + t];
    __syncthreads();

    const int cl = labels[n];
    const float ratio = *ratio_p;

    float s0 = score[n * 4 + 0], s1 = score[n * 4 + 1];
    float s2 = score[n * 4 + 2], s3 = score[n * 4 + 3];
    int ks = 0; float bs = s0;                   // strict <: first-min == jnp first-max
    if (s1 < bs) { bs = s1; ks = 1; }
    if (s2 < bs) { bs = s2; ks = 2; }
    if (s3 < bs) { bs = s3; ks = 3; }

    const int base = (cl * 4 + ks) * C_CLS;
    const float gll = gdiag[base + cl];
    float aug = -INFINITY;
    if (t < C_CLS) {
        const float4* wr = (const float4*)(weight + t * A_DIM);
        const float4* xr = (const float4*)xs;
        float acc = bias[t];
        #pragma unroll
        for (int j = 0; j < 32; ++j) {
            float4 a = xr[j], b = wr[j];
            acc += a.x * b.x + a.y * b.y + a.z * b.z + a.w * b.w;
        }
        y[(size_t)n * C_CLS + t] = acc;
        aug = acc + 0.5f * ratio * (gdiag[base + t] - 2.0f * gcol[base + t] + gll);
    }

    float m = aug;
    #pragma unroll
    for (int off = 32; off; off >>= 1) m = fmaxf(m, __shfl_xor(m, off, 64));
    if ((t & 63) == 0) red[t >> 6] = m;
    __syncthreads();
    m = fmaxf(red[0], red[1]);

    float e = (t < C_CLS) ? expf(aug - m) : 0.0f;
    #pragma unroll
    for (int off = 32; off; off >>= 1) e += __shfl_xor(e, off, 64);
    if ((t & 63) == 0) red2[t >> 6] = e;
    if (t == cl) acl_s = aug;
    __syncthreads();

    if (t == 0) {
        float sum = red2[0] + red2[1];
        float lp = acl_s - m - logf(sum);
        atomicAdd(loss, -lp * (1.0f / (float)N_S));
    }
}

// ---------------------------------------------------------------------------
extern "C" void kernel_launch(void* const* d_in, const int* in_sizes, int n_in,
                              void* d_out, int out_size, void* d_ws, size_t ws_size,
                              hipStream_t stream) {
    const float* features = (const float*)d_in[0];
    const float* weight   = (const float*)d_in[1];
    const float* bias     = (const float*)d_in[2];
    // d_in[3] = pi : unused (q is one-hot for any pi > 0; argmax unaffected)
    const float* mu       = (const float*)d_in[4];
    const float* sigma    = (const float*)d_in[5];
    const int*   labels   = (const int*)d_in[6];
    const float* ratio    = (const float*)d_in[7];

    float* out   = (float*)d_out;   // [0] = loss, [1..204800] = y
    float* yout  = out + 1;
    float* score = (float*)d_ws;                  // 8192 f32
    float* gdiag = score + N_S * K_CL;            // 40000 f32
    float* gcol  = gdiag + C_CLS * K_CL * C_CLS;  // 40000 f32
    int*   cntg  = (int*)(gcol + C_CLS * K_CL * C_CLS);  // 100 int
    int*   idxg  = cntg + C_CLS;                          // 100*96 int

    hipMemsetAsync(d_out, 0, sizeof(float), stream);   // zero the loss accumulator

    k_bucket      <<<dim3(1),            dim3(256), 0, stream>>>(labels, cntg, idxg);
    k_invert_score<<<dim3(C_CLS * K_CL), dim3(512), 0, stream>>>(sigma, mu, features, cntg, idxg, score);
    k_gprep       <<<dim3(C_CLS * K_CL), dim3(256), 0, stream>>>(sigma, weight, gdiag, gcol);
    k_out         <<<dim3(N_S),          dim3(128), 0, stream>>>(features, weight, bias, labels,
                                                                 score, gdiag, gcol, ratio, yout, out);
}

// Round 9
// 341.891 us; speedup vs baseline: 1.2604x; 1.0347x over previous
//
#include <hip/hip_runtime.h>
#include <hip/hip_bf16.h>
#include <cmath>

#define N_S    2048
#define C_CLS  100
#define K_CL   4
#define A_DIM  128
#define LDSROW 132   // padded row stride: breaks row-power-of-2 bank aliasing
#define NB     16    // GJ panel width
#define MAXPER 96    // max samples per class (mean 20.5; >15 sigma headroom)

// ---------------------------------------------------------------------------
// Kernel 0: bucket samples by class
// ---------------------------------------------------------------------------
__global__ __launch_bounds__(256) void k_bucket(
    const int* __restrict__ labels, int* __restrict__ cntg, int* __restrict__ idxg)
{
    __shared__ int cntL[C_CLS];
    const int t = threadIdx.x;
    if (t < C_CLS) cntL[t] = 0;
    __syncthreads();
    for (int n = t; n < N_S; n += 256) {
        int c = labels[n];
        int slot = atomicAdd(&cntL[c], 1);
        if (slot < MAXPER) idxg[c * MAXPER + slot] = n;
    }
    __syncthreads();
    if (t < C_CLS) cntg[t] = min(cntL[t], MAXPER);
}

// ===========================================================================
// Shared device routine: blocked Gauss-Jordan of As (in LDS), returns logdet
// in wave 0's lanes. Identical math to the round-8 passing kernel.
// ===========================================================================
__device__ __forceinline__ float gj_invert_lds(
    float* As, float* Rbuf, float* DinvS, int tid)
{
    const int lane = tid & 63;
    const int wv   = tid >> 6;
    float logdet = 0.0f;                 // valid in wave 0 only

    for (int t = 0; t < 8; ++t) {
        const int p0 = NB * t;

        // (a) wave 0: invert 16x16 diagonal block in registers (shfl GJ)
        if (wv == 0) {
            const int r = lane >> 2, cg = lane & 3;
            float4 dv = *(const float4*)&As[(p0 + r) * LDSROW + p0 + 4 * cg];
            #pragma unroll
            for (int p = 0; p < NB; ++p) {
                const int sel = p & 3, pr4 = p >> 2;
                float te = (sel == 0) ? dv.x : (sel == 1) ? dv.y : (sel == 2) ? dv.z : dv.w;
                float piv = __shfl(te, (p << 2) | pr4, 64);
                float ip  = 1.0f / piv;
                logdet += __logf(piv);
                const int rowsrc = (p << 2) | cg;
                float4 prs;
                prs.x = __shfl(dv.x, rowsrc, 64) * ip;
                prs.y = __shfl(dv.y, rowsrc, 64) * ip;
                prs.z = __shfl(dv.z, rowsrc, 64) * ip;
                prs.w = __shfl(dv.w, rowsrc, 64) * ip;
                if (cg == pr4) (&prs.x)[sel] = ip;           // (p,p) -> 1/piv
                float f = __shfl(te, (lane & ~3) | pr4, 64); // my row's col-p value
                if (r == p) {
                    dv = prs;
                } else {
                    dv.x -= f * prs.x; dv.y -= f * prs.y;
                    dv.z -= f * prs.z; dv.w -= f * prs.w;
                    if (cg == pr4) (&dv.x)[sel] = -f * ip;   // col p: assign
                }
            }
            DinvS[r * 17 + 4 * cg + 0] = dv.x;
            DinvS[r * 17 + 4 * cg + 1] = dv.y;
            DinvS[r * 17 + 4 * cg + 2] = dv.z;
            DinvS[r * 17 + 4 * cg + 3] = dv.w;
        }
        __syncthreads();   // b1: Dinv ready

        // (b) Rnew = Dinv * A[P,:] into Rbuf; panel cols get Dinv itself.
        {
            const int rr = tid >> 5, j4c = tid & 31;
            float4 o;
            if ((j4c >> 2) == t) {
                const int cg = j4c & 3;
                o.x = DinvS[rr * 17 + 4 * cg + 0];
                o.y = DinvS[rr * 17 + 4 * cg + 1];
                o.z = DinvS[rr * 17 + 4 * cg + 2];
                o.w = DinvS[rr * 17 + 4 * cg + 3];
            } else {
                o.x = 0.f; o.y = 0.f; o.z = 0.f; o.w = 0.f;
                #pragma unroll 4
                for (int k = 0; k < NB; ++k) {
                    const float a = DinvS[rr * 17 + k];          // broadcast
                    const float4 s4 = *(const float4*)&As[(p0 + k) * LDSROW + 4 * j4c];
                    o.x += a * s4.x; o.y += a * s4.y; o.z += a * s4.z; o.w += a * s4.w;
                }
            }
            *(float4*)&Rbuf[rr * A_DIM + 4 * j4c] = o;
        }
        __syncthreads();   // b2: Rnew ready (As panel rows still OLD)

        // (c) rank-16 update of 112 non-panel rows: per thread 4 rows x 8 cols.
        if (tid < 448) {
            const int rgi = tid >> 4;                 // 0..27 non-panel row group
            const int cp  = tid & 15;                 // j4 pair
            const int rga = (rgi < 4 * t) ? rgi : rgi + 4;
            const int row0 = 4 * rga;
            const int c0 = 8 * cp, c1 = 8 * cp + 4;
            const bool pcol = ((cp >> 1) == t);       // my 2 j4s are the panel cols
            float4 a00, a01, a10, a11, a20, a21, a30, a31;
            if (pcol) {
                a00 = a01 = a10 = a11 = a20 = a21 = a30 = a31 = (float4){0, 0, 0, 0};
            } else {
                a00 = *(const float4*)&As[(row0 + 0) * LDSROW + c0];
                a01 = *(const float4*)&As[(row0 + 0) * LDSROW + c1];
                a10 = *(const float4*)&As[(row0 + 1) * LDSROW + c0];
                a11 = *(const float4*)&As[(row0 + 1) * LDSROW + c1];
                a20 = *(const float4*)&As[(row0 + 2) * LDSROW + c0];
                a21 = *(const float4*)&As[(row0 + 2) * LDSROW + c1];
                a30 = *(const float4*)&As[(row0 + 3) * LDSROW + c0];
                a31 = *(const float4*)&As[(row0 + 3) * LDSROW + c1];
            }
            #pragma unroll 4
            for (int k = 0; k < NB; ++k) {
                const float4 r0 = *(const float4*)&Rbuf[k * A_DIM + c0];
                const float4 r1 = *(const float4*)&Rbuf[k * A_DIM + c1];
                const float f0 = As[(row0 + 0) * LDSROW + p0 + k];
                const float f1 = As[(row0 + 1) * LDSROW + p0 + k];
                const float f2 = As[(row0 + 2) * LDSROW + p0 + k];
                const float f3 = As[(row0 + 3) * LDSROW + p0 + k];
                a00.x -= f0 * r0.x; a00.y -= f0 * r0.y; a00.z -= f0 * r0.z; a00.w -= f0 * r0.w;
                a01.x -= f0 * r1.x; a01.y -= f0 * r1.y; a01.z -= f0 * r1.z; a01.w -= f0 * r1.w;
                a10.x -= f1 * r0.x; a10.y -= f1 * r0.y; a10.z -= f1 * r0.z; a10.w -= f1 * r0.w;
                a11.x -= f1 * r1.x; a11.y -= f1 * r1.y; a11.z -= f1 * r1.z; a11.w -= f1 * r1.w;
                a20.x -= f2 * r0.x; a20.y -= f2 * r0.y; a20.z -= f2 * r0.z; a20.w -= f2 * r0.w;
                a21.x -= f2 * r1.x; a21.y -= f2 * r1.y; a21.z -= f2 * r1.z; a21.w -= f2 * r1.w;
                a30.x -= f3 * r0.x; a30.y -= f3 * r0.y; a30.z -= f3 * r0.z; a30.w -= f3 * r0.w;
                a31.x -= f3 * r1.x; a31.y -= f3 * r1.y; a31.z -= f3 * r1.z; a31.w -= f3 * r1.w;
            }
            *(float4*)&As[(row0 + 0) * LDSROW + c0] = a00;
            *(float4*)&As[(row0 + 0) * LDSROW + c1] = a01;
            *(float4*)&As[(row0 + 1) * LDSROW + c0] = a10;
            *(float4*)&As[(row0 + 1) * LDSROW + c1] = a11;
            *(float4*)&As[(row0 + 2) * LDSROW + c0] = a20;
            *(float4*)&As[(row0 + 2) * LDSROW + c1] = a21;
            *(float4*)&As[(row0 + 3) * LDSROW + c0] = a30;
            *(float4*)&As[(row0 + 3) * LDSROW + c1] = a31;
        }
        // copyback Rbuf -> As panel rows (panel rows untouched by the update)
        {
            const int rr = tid >> 5, j4c = tid & 31;
            *(float4*)&As[(p0 + rr) * LDSROW + 4 * j4c] =
                *(const float4*)&Rbuf[rr * A_DIM + 4 * j4c];
        }
        __syncthreads();   // b3: panel done
    }
    return logdet;
}

// ---------------------------------------------------------------------------
// Kernel 1a (SPLIT): invert sigma[bid] -> sinv[bid] (coalesced), logdet out.
// ---------------------------------------------------------------------------
__global__ __launch_bounds__(512, 2) void k_invert(
    const float* __restrict__ sigma, float* __restrict__ sinv,
    float* __restrict__ logdets)
{
    __shared__ __align__(16) float As[A_DIM * LDSROW];   // 67.6 KB
    __shared__ __align__(16) float Rbuf[NB * A_DIM];     // 8.2 KB
    __shared__ float DinvS[NB * 17];

    const int tid = threadIdx.x;
    const int bid = blockIdx.x;

    const float4* src = (const float4*)(sigma + (size_t)bid * A_DIM * A_DIM);
    for (int e4 = tid; e4 < A_DIM * 32; e4 += 512) {
        int i = e4 >> 5, j4 = e4 & 31;
        *(float4*)&As[i * LDSROW + 4 * j4] = src[e4];
    }
    __syncthreads();

    float logdet = gj_invert_lds(As, Rbuf, DinvS, tid);

    // coalesced writeback of Sigma^{-1}
    float4* dst = (float4*)(sinv + (size_t)bid * A_DIM * A_DIM);
    for (int e4 = tid; e4 < A_DIM * 32; e4 += 512) {
        int i = e4 >> 5, j4 = e4 & 31;
        dst[e4] = *(const float4*)&As[i * LDSROW + 4 * j4];
    }
    if (tid == 0) logdets[bid] = logdet;
}

// ---------------------------------------------------------------------------
// Kernel 1b (SPLIT): stage sinv[bid] (L2-resident) into LDS, per-sample
// quadratic form for class cl = bid>>2: score = d^T Sinv d + logdet.
// ---------------------------------------------------------------------------
__global__ __launch_bounds__(512, 2) void k_score(
    const float* __restrict__ sinv, const float* __restrict__ logdets,
    const float* __restrict__ mu, const float* __restrict__ features,
    const int* __restrict__ cntg, const int* __restrict__ idxg,
    float* __restrict__ score)
{
    __shared__ __align__(16) float As[A_DIM * LDSROW];

    const int tid  = threadIdx.x;
    const int bid  = blockIdx.x;
    const int cl   = bid >> 2;
    const int lane = tid & 63;
    const int wv   = tid >> 6;

    const float4* src = (const float4*)(sinv + (size_t)bid * A_DIM * A_DIM);
    for (int e4 = tid; e4 < A_DIM * 32; e4 += 512) {
        int i = e4 >> 5, j4 = e4 & 31;
        *(float4*)&As[i * LDSROW + 4 * j4] = src[e4];
    }
    __syncthreads();

    const float ld = logdets[bid];
    const float m0 = mu[(size_t)bid * A_DIM + lane];
    const float m1 = mu[(size_t)bid * A_DIM + 64 + lane];
    const int cnt = cntg[cl];
    for (int s = wv; s < cnt; s += 8) {
        const int n = idxg[cl * MAXPER + s];
        float d0 = features[(size_t)n * A_DIM + lane]      - m0;
        float d1 = features[(size_t)n * A_DIM + 64 + lane] - m1;
        float p0v = 0.f, p1v = 0.f;
        for (int i = 0; i < 64; ++i) {
            float b = __shfl(d0, i, 64);
            p0v += b * As[i * LDSROW + lane];
            p1v += b * As[i * LDSROW + 64 + lane];
        }
        for (int i = 0; i < 64; ++i) {
            float b = __shfl(d1, i, 64);
            p0v += b * As[(i + 64) * LDSROW + lane];
            p1v += b * As[(i + 64) * LDSROW + 64 + lane];
        }
        float q = d0 * p0v + d1 * p1v;
        #pragma unroll
        for (int off = 32; off; off >>= 1) q += __shfl_xor(q, off, 64);
        if (lane == 0) score[n * K_CL + (bid & 3)] = q + ld;
    }
}

// ---------------------------------------------------------------------------
// Kernel 1 (FALLBACK, fused — round-8 passing version) used if ws too small
// ---------------------------------------------------------------------------
__global__ __launch_bounds__(512, 2) void k_invert_score(
    const float* __restrict__ sigma, const float* __restrict__ mu,
    const float* __restrict__ features, const int* __restrict__ cntg,
    const int* __restrict__ idxg, float* __restrict__ score)
{
    __shared__ __align__(16) float As[A_DIM * LDSROW];
    __shared__ __align__(16) float Rbuf[NB * A_DIM];
    __shared__ float DinvS[NB * 17];
    __shared__ float ldS;

    const int tid  = threadIdx.x;
    const int bid  = blockIdx.x;
    const int cl   = bid >> 2;
    const int lane = tid & 63;
    const int wv   = tid >> 6;

    const float4* src = (const float4*)(sigma + (size_t)bid * A_DIM * A_DIM);
    for (int e4 = tid; e4 < A_DIM * 32; e4 += 512) {
        int i = e4 >> 5, j4 = e4 & 31;
        *(float4*)&As[i * LDSROW + 4 * j4] = src[e4];
    }
    __syncthreads();

    float logdet = gj_invert_lds(As, Rbuf, DinvS, tid);

    if (tid == 0) ldS = logdet;
    __syncthreads();
    const float ld = ldS;

    const float m0 = mu[(size_t)bid * A_DIM + lane];
    const float m1 = mu[(size_t)bid * A_DIM + 64 + lane];
    const int cnt = cntg[cl];
    for (int s = wv; s < cnt; s += 8) {
        const int n = idxg[cl * MAXPER + s];
        float d0 = features[(size_t)n * A_DIM + lane]      - m0;
        float d1 = features[(size_t)n * A_DIM + 64 + lane] - m1;
        float p0v = 0.f, p1v = 0.f;
        for (int i = 0; i < 64; ++i) {
            float b = __shfl(d0, i, 64);
            p0v += b * As[i * LDSROW + lane];
            p1v += b * As[i * LDSROW + 64 + lane];
        }
        for (int i = 0; i < 64; ++i) {
            float b = __shfl(d1, i, 64);
            p0v += b * As[(i + 64) * LDSROW + lane];
            p1v += b * As[(i + 64) * LDSROW + 64 + lane];
        }
        float q = d0 * p0v + d1 * p1v;
        #pragma unroll
        for (int off = 32; off; off >>= 1) q += __shfl_xor(q, off, 64);
        if (lane == 0) score[n * K_CL + (bid & 3)] = q + ld;
    }
}

// ---------------------------------------------------------------------------
// Kernel 2: per (cl,k): gdiag[c]=W[c] S W[c]^T, gcol[c]=W[c] S W[cl]^T
// ---------------------------------------------------------------------------
__global__ __launch_bounds__(256) void k_gprep(
    const float* __restrict__ sigma, const float* __restrict__ weight,
    float* __restrict__ gdiag, float* __restrict__ gcol)
{
    __shared__ __align__(16) float Ss[A_DIM * A_DIM];   // 64 KB
    __shared__ __align__(16) float Ws[C_CLS * A_DIM];   // 51.2 KB
    const int tid = threadIdx.x, bid = blockIdx.x;
    const int cl  = bid >> 2;
    const int lane = tid & 63, wv = tid >> 6;

    const float4* src = (const float4*)(sigma + (size_t)bid * A_DIM * A_DIM);
    for (int e4 = tid; e4 < A_DIM * 32; e4 += 256)
        ((float4*)Ss)[e4] = src[e4];
    const float4* wsrc = (const float4*)weight;
    for (int e4 = tid; e4 < C_CLS * 32; e4 += 256)
        ((float4*)Ws)[e4] = wsrc[e4];
    __syncthreads();

    const float wc0 = Ws[cl * A_DIM + lane];
    const float wc1 = Ws[cl * A_DIM + 64 + lane];
    const int cbeg = wv * 25;               // 4 waves x 25 classes = 100

    for (int g = 0; g < 5; ++g) {           // 5 uniform groups of 5 rows
        const int c0 = cbeg + g * 5;
        const float* w0 = &Ws[(c0 + 0) * A_DIM];
        const float* w1 = &Ws[(c0 + 1) * A_DIM];
        const float* w2 = &Ws[(c0 + 2) * A_DIM];
        const float* w3 = &Ws[(c0 + 3) * A_DIM];
        const float* w4 = &Ws[(c0 + 4) * A_DIM];
        float h00 = 0.f, h01 = 0.f, h02 = 0.f, h03 = 0.f, h04 = 0.f;  // j = lane
        float h10 = 0.f, h11 = 0.f, h12 = 0.f, h13 = 0.f, h14 = 0.f;  // j = lane+64
        #pragma unroll 4
        for (int i = 0; i < A_DIM; ++i) {
            const float s0 = Ss[i * A_DIM + lane];
            const float s1 = Ss[i * A_DIM + 64 + lane];
            const float b0 = w0[i], b1 = w1[i], b2 = w2[i], b3 = w3[i], b4 = w4[i];
            h00 += b0 * s0; h10 += b0 * s1;
            h01 += b1 * s0; h11 += b1 * s1;
            h02 += b2 * s0; h12 += b2 * s1;
            h03 += b3 * s0; h13 += b3 * s1;
            h04 += b4 * s0; h14 += b4 * s1;
        }
        #define GOUT(HA, HB, CC)                                            \
        {                                                                   \
            const int c = c0 + (CC);                                        \
            float pd = (HA) * Ws[c * A_DIM + lane]                          \
                     + (HB) * Ws[c * A_DIM + 64 + lane];                    \
            float pc = (HA) * wc0 + (HB) * wc1;                             \
            _Pragma("unroll")                                               \
            for (int off = 32; off; off >>= 1) {                            \
                pd += __shfl_xor(pd, off, 64);                              \
                pc += __shfl_xor(pc, off, 64);                              \
            }                                                               \
            if (lane == 0) {                                                \
                gdiag[bid * C_CLS + c] = pd;                                \
                gcol [bid * C_CLS + c] = pc;                                \
            }                                                               \
        }
        GOUT(h00, h10, 0)
        GOUT(h01, h11, 1)
        GOUT(h02, h12, 2)
        GOUT(h03, h13, 3)
        GOUT(h04, h14, 4)
        #undef GOUT
    }
}

// ---------------------------------------------------------------------------
// Kernel 3 (fused fc + final)
// ---------------------------------------------------------------------------
__global__ __launch_bounds__(128) void k_out(
    const float* __restrict__ features, const float* __restrict__ weight,
    const float* __restrict__ bias, const int* __restrict__ labels,
    const float* __restrict__ score, const float* __restrict__ gdiag,
    const float* __restrict__ gcol, const float* __restrict__ ratio_p,
    float* __restrict__ y, float* __restrict__ loss)
{
    __shared__ __align__(16) float xs[A_DIM];
    __shared__ float red[2], red2[2], acl_s;
    const int n = blockIdx.x, t = threadIdx.x;
    xs[t] = features[(size_t)n * A_DIM + t];
    __syncthreads();

    const int cl = labels[n];
    const float ratio = *ratio_p;

    float s0 = score[n * 4 + 0], s1 = score[n * 4 + 1];
    float s2 = score[n * 4 + 2], s3 = score[n * 4 + 3];
    int ks = 0; float bs = s0;                   // strict <: first-min == jnp first-max
    if (s1 < bs) { bs = s1; ks = 1; }
    if (s2 < bs) { bs = s2; ks = 2; }
    if (s3 < bs) { bs = s3; ks = 3; }

    const int base = (cl * 4 + ks) * C_CLS;
    const float gll = gdiag[base + cl];
    float aug = -INFINITY;
    if (t < C_CLS) {
        const float4* wr = (const float4*)(weight + t * A_DIM);
        const float4* xr = (const float4*)xs;
        float acc = bias[t];
        #pragma unroll
        for (int j = 0; j < 32; ++j) {
            float4 a = xr[j], b = wr[j];
            acc += a.x * b.x + a.y * b.y + a.z * b.z + a.w * b.w;
        }
        y[(size_t)n * C_CLS + t] = acc;
        aug = acc + 0.5f * ratio * (gdiag[base + t] - 2.0f * gcol[base + t] + gll);
    }

    float m = aug;
    #pragma unroll
    for (int off = 32; off; off >>= 1) m = fmaxf(m, __shfl_xor(m, off, 64));
    if ((t & 63) == 0) red[t >> 6] = m;
    __syncthreads();
    m = fmaxf(red[0], red[1]);

    float e = (t < C_CLS) ? expf(aug - m) : 0.0f;
    #pragma unroll
    for (int off = 32; off; off >>= 1) e += __shfl_xor(e, off, 64);
    if ((t & 63) == 0) red2[t >> 6] = e;
    if (t == cl) acl_s = aug;
    __syncthreads();

    if (t == 0) {
        float sum = red2[0] + red2[1];
        float lp = acl_s - m - logf(sum);
        atomicAdd(loss, -lp * (1.0f / (float)N_S));
    }
}

// ---------------------------------------------------------------------------
extern "C" void kernel_launch(void* const* d_in, const int* in_sizes, int n_in,
                              void* d_out, int out_size, void* d_ws, size_t ws_size,
                              hipStream_t stream) {
    const float* features = (const float*)d_in[0];
    const float* weight   = (const float*)d_in[1];
    const float* bias     = (const float*)d_in[2];
    // d_in[3] = pi : unused (q is one-hot for any pi > 0; argmax unaffected)
    const float* mu       = (const float*)d_in[4];
    const float* sigma    = (const float*)d_in[5];
    const int*   labels   = (const int*)d_in[6];
    const float* ratio    = (const float*)d_in[7];

    float* out   = (float*)d_out;   // [0] = loss, [1..204800] = y
    float* yout  = out + 1;

    float* score   = (float*)d_ws;                       // 8192 f32
    float* gdiag   = score + N_S * K_CL;                 // 40000 f32
    float* gcol    = gdiag + C_CLS * K_CL * C_CLS;       // 40000 f32
    int*   cntg    = (int*)(gcol + C_CLS * K_CL * C_CLS);// 100 int
    int*   idxg    = cntg + C_CLS;                       // 9600 int
    float* logdets = (float*)(idxg + C_CLS * MAXPER);    // 400 f32
    float* sinvbuf = logdets + 512;                      // 400*16384 f32
    const size_t need_bytes =
        ((char*)(sinvbuf + (size_t)C_CLS * K_CL * A_DIM * A_DIM)) - (char*)d_ws;
    const bool use_split = (ws_size >= need_bytes);

    hipMemsetAsync(d_out, 0, sizeof(float), stream);   // zero the loss accumulator

    k_bucket<<<dim3(1), dim3(256), 0, stream>>>(labels, cntg, idxg);
    if (use_split) {
        k_invert<<<dim3(C_CLS * K_CL), dim3(512), 0, stream>>>(sigma, sinvbuf, logdets);
        k_score <<<dim3(C_CLS * K_CL), dim3(512), 0, stream>>>(sinvbuf, logdets, mu,
                                                               features, cntg, idxg, score);
    } else {
        k_invert_score<<<dim3(C_CLS * K_CL), dim3(512), 0, stream>>>(sigma, mu, features,
                                                                     cntg, idxg, score);
    }
    k_gprep<<<dim3(C_CLS * K_CL), dim3(256), 0, stream>>>(sigma, weight, gdiag, gcol);
    k_out  <<<dim3(N_S),          dim3(128), 0, stream>>>(features, weight, bias, labels,
                                                          score, gdiag, gcol, ratio, yout, out);
}

// Round 10
// 253.096 us; speedup vs baseline: 1.7025x; 1.3508x over previous
//
#include <hip/hip_runtime.h>
#include <hip/hip_bf16.h>
#include <cmath>

#define N_S    2048
#define C_CLS  100
#define K_CL   4
#define A_DIM  128
#define LDSROW 132   // padded row stride: breaks row-power-of-2 bank aliasing
#define NB     16    // GJ panel width
#define MAXPER 96    // max samples per class (mean 20.5; >15 sigma headroom)

// ---------------------------------------------------------------------------
// Kernel 0: bucket samples by class
// ---------------------------------------------------------------------------
__global__ __launch_bounds__(256) void k_bucket(
    const int* __restrict__ labels, int* __restrict__ cntg, int* __restrict__ idxg)
{
    __shared__ int cntL[C_CLS];
    const int t = threadIdx.x;
    if (t < C_CLS) cntL[t] = 0;
    __syncthreads();
    for (int n = t; n < N_S; n += 256) {
        int c = labels[n];
        int slot = atomicAdd(&cntL[c], 1);
        if (slot < MAXPER) idxg[c * MAXPER + slot] = n;
    }
    __syncthreads();
    if (t < C_CLS) cntg[t] = min(cntL[t], MAXPER);
}

// ===========================================================================
// Blocked Gauss-Jordan of As (in LDS), returns logdet in wave 0's lanes.
// Identical math to the rounds 8/9 passing kernels (k_invert was NOT in the
// top-5 => this part is clean).
// ===========================================================================
__device__ __forceinline__ float gj_invert_lds(
    float* As, float* Rbuf, float* DinvS, int tid)
{
    const int lane = tid & 63;
    const int wv   = tid >> 6;
    float logdet = 0.0f;                 // valid in wave 0 only

    for (int t = 0; t < 8; ++t) {
        const int p0 = NB * t;

        // (a) wave 0: invert 16x16 diagonal block in registers (shfl GJ)
        if (wv == 0) {
            const int r = lane >> 2, cg = lane & 3;
            float4 dv = *(const float4*)&As[(p0 + r) * LDSROW + p0 + 4 * cg];
            #pragma unroll
            for (int p = 0; p < NB; ++p) {
                const int sel = p & 3, pr4 = p >> 2;
                float te = (sel == 0) ? dv.x : (sel == 1) ? dv.y : (sel == 2) ? dv.z : dv.w;
                float piv = __shfl(te, (p << 2) | pr4, 64);
                float ip  = 1.0f / piv;
                logdet += __logf(piv);
                const int rowsrc = (p << 2) | cg;
                float4 prs;
                prs.x = __shfl(dv.x, rowsrc, 64) * ip;
                prs.y = __shfl(dv.y, rowsrc, 64) * ip;
                prs.z = __shfl(dv.z, rowsrc, 64) * ip;
                prs.w = __shfl(dv.w, rowsrc, 64) * ip;
                if (cg == pr4) (&prs.x)[sel] = ip;           // (p,p) -> 1/piv
                float f = __shfl(te, (lane & ~3) | pr4, 64); // my row's col-p value
                if (r == p) {
                    dv = prs;
                } else {
                    dv.x -= f * prs.x; dv.y -= f * prs.y;
                    dv.z -= f * prs.z; dv.w -= f * prs.w;
                    if (cg == pr4) (&dv.x)[sel] = -f * ip;   // col p: assign
                }
            }
            DinvS[r * 17 + 4 * cg + 0] = dv.x;
            DinvS[r * 17 + 4 * cg + 1] = dv.y;
            DinvS[r * 17 + 4 * cg + 2] = dv.z;
            DinvS[r * 17 + 4 * cg + 3] = dv.w;
        }
        __syncthreads();   // b1: Dinv ready

        // (b) Rnew = Dinv * A[P,:] into Rbuf; panel cols get Dinv itself.
        {
            const int rr = tid >> 5, j4c = tid & 31;
            float4 o;
            if ((j4c >> 2) == t) {
                const int cg = j4c & 3;
                o.x = DinvS[rr * 17 + 4 * cg + 0];
                o.y = DinvS[rr * 17 + 4 * cg + 1];
                o.z = DinvS[rr * 17 + 4 * cg + 2];
                o.w = DinvS[rr * 17 + 4 * cg + 3];
            } else {
                o.x = 0.f; o.y = 0.f; o.z = 0.f; o.w = 0.f;
                #pragma unroll 4
                for (int k = 0; k < NB; ++k) {
                    const float a = DinvS[rr * 17 + k];          // broadcast
                    const float4 s4 = *(const float4*)&As[(p0 + k) * LDSROW + 4 * j4c];
                    o.x += a * s4.x; o.y += a * s4.y; o.z += a * s4.z; o.w += a * s4.w;
                }
            }
            *(float4*)&Rbuf[rr * A_DIM + 4 * j4c] = o;
        }
        __syncthreads();   // b2: Rnew ready (As panel rows still OLD)

        // (c) rank-16 update of 112 non-panel rows: per thread 4 rows x 8 cols.
        if (tid < 448) {
            const int rgi = tid >> 4;                 // 0..27 non-panel row group
            const int cp  = tid & 15;                 // j4 pair
            const int rga = (rgi < 4 * t) ? rgi : rgi + 4;
            const int row0 = 4 * rga;
            const int c0 = 8 * cp, c1 = 8 * cp + 4;
            const bool pcol = ((cp >> 1) == t);       // my 2 j4s are the panel cols
            float4 a00, a01, a10, a11, a20, a21, a30, a31;
            if (pcol) {
                a00 = a01 = a10 = a11 = a20 = a21 = a30 = a31 = (float4){0, 0, 0, 0};
            } else {
                a00 = *(const float4*)&As[(row0 + 0) * LDSROW + c0];
                a01 = *(const float4*)&As[(row0 + 0) * LDSROW + c1];
                a10 = *(const float4*)&As[(row0 + 1) * LDSROW + c0];
                a11 = *(const float4*)&As[(row0 + 1) * LDSROW + c1];
                a20 = *(const float4*)&As[(row0 + 2) * LDSROW + c0];
                a21 = *(const float4*)&As[(row0 + 2) * LDSROW + c1];
                a30 = *(const float4*)&As[(row0 + 3) * LDSROW + c0];
                a31 = *(const float4*)&As[(row0 + 3) * LDSROW + c1];
            }
            #pragma unroll 4
            for (int k = 0; k < NB; ++k) {
                const float4 r0 = *(const float4*)&Rbuf[k * A_DIM + c0];
                const float4 r1 = *(const float4*)&Rbuf[k * A_DIM + c1];
                const float f0 = As[(row0 + 0) * LDSROW + p0 + k];
                const float f1 = As[(row0 + 1) * LDSROW + p0 + k];
                const float f2 = As[(row0 + 2) * LDSROW + p0 + k];
                const float f3 = As[(row0 + 3) * LDSROW + p0 + k];
                a00.x -= f0 * r0.x; a00.y -= f0 * r0.y; a00.z -= f0 * r0.z; a00.w -= f0 * r0.w;
                a01.x -= f0 * r1.x; a01.y -= f0 * r1.y; a01.z -= f0 * r1.z; a01.w -= f0 * r1.w;
                a10.x -= f1 * r0.x; a10.y -= f1 * r0.y; a10.z -= f1 * r0.z; a10.w -= f1 * r0.w;
                a11.x -= f1 * r1.x; a11.y -= f1 * r1.y; a11.z -= f1 * r1.z; a11.w -= f1 * r1.w;
                a20.x -= f2 * r0.x; a20.y -= f2 * r0.y; a20.z -= f2 * r0.z; a20.w -= f2 * r0.w;
                a21.x -= f2 * r1.x; a21.y -= f2 * r1.y; a21.z -= f2 * r1.z; a21.w -= f2 * r1.w;
                a30.x -= f3 * r0.x; a30.y -= f3 * r0.y; a30.z -= f3 * r0.z; a30.w -= f3 * r0.w;
                a31.x -= f3 * r1.x; a31.y -= f3 * r1.y; a31.z -= f3 * r1.z; a31.w -= f3 * r1.w;
            }
            *(float4*)&As[(row0 + 0) * LDSROW + c0] = a00;
            *(float4*)&As[(row0 + 0) * LDSROW + c1] = a01;
            *(float4*)&As[(row0 + 1) * LDSROW + c0] = a10;
            *(float4*)&As[(row0 + 1) * LDSROW + c1] = a11;
            *(float4*)&As[(row0 + 2) * LDSROW + c0] = a20;
            *(float4*)&As[(row0 + 2) * LDSROW + c1] = a21;
            *(float4*)&As[(row0 + 3) * LDSROW + c0] = a30;
            *(float4*)&As[(row0 + 3) * LDSROW + c1] = a31;
        }
        // copyback Rbuf -> As panel rows (panel rows untouched by the update)
        {
            const int rr = tid >> 5, j4c = tid & 31;
            *(float4*)&As[(p0 + rr) * LDSROW + 4 * j4c] =
                *(const float4*)&Rbuf[rr * A_DIM + 4 * j4c];
        }
        __syncthreads();   // b3: panel done
    }
    return logdet;
}

// ---------------------------------------------------------------------------
// Kernel 1 (FUSED, NEW TAIL): blocked-GJ invert sigma[bid] in LDS, then a
// BATCHED score tail: chunks of 16 samples staged as D=[16][128] in LDS
// (reusing the GJ Rbuf), thread (s=tid>>5, jg=tid&31) computes
// p = sum_i D[s][i] * Sinv[i][4jg..] (broadcast + conflict-free b128 reads),
// partial = p . D[s][4jg..], reduced via padded [16][33] LDS.
// No shfl, tiny live set -> the round-6..9 ~69MB scratch signature should die.
// ---------------------------------------------------------------------------
__global__ __launch_bounds__(512, 2) void k_invert_score(
    const float* __restrict__ sigma, const float* __restrict__ mu,
    const float* __restrict__ features, const int* __restrict__ cntg,
    const int* __restrict__ idxg, float* __restrict__ score)
{
    __shared__ __align__(16) float As[A_DIM * LDSROW];          // 67.6 KB
    __shared__ __align__(16) float Scratch[NB * A_DIM + 16*33]; // 10.3 KB (Rbuf / Dbuf+Par)
    __shared__ float DinvS[NB * 17];
    __shared__ float ldS;

    const int tid = threadIdx.x;
    const int bid = blockIdx.x;          // cl*K_CL + k
    const int cl  = bid >> 2;

    // ---- stage sigma (coalesced b128) ----
    const float4* src = (const float4*)(sigma + (size_t)bid * A_DIM * A_DIM);
    for (int e4 = tid; e4 < A_DIM * 32; e4 += 512) {
        int i = e4 >> 5, j4 = e4 & 31;
        *(float4*)&As[i * LDSROW + 4 * j4] = src[e4];
    }
    __syncthreads();

    float logdet = gj_invert_lds(As, Scratch, DinvS, tid);
    if (tid == 0) ldS = logdet;
    __syncthreads();
    const float ld = ldS;
    // As = Sigma^{-1}

    // ---- batched per-sample quadratic form ----
    float* Dbuf = Scratch;                  // [16][128]
    float* Par  = Scratch + NB * A_DIM;     // [16][33] padded
    const int s16 = tid >> 5;               // sample slot 0..15
    const int fc  = tid & 31;               // float4 column 0..31
    const int cnt = cntg[cl];
    const float4 muv = ((const float4*)mu)[bid * 32 + fc];

    for (int c0 = 0; c0 < cnt; c0 += 16) {
        const int m = cnt - c0 < 16 ? cnt - c0 : 16;
        // stage D = x - mu for this chunk
        if (s16 < m) {
            const int n = idxg[cl * MAXPER + c0 + s16];
            const float4 f = ((const float4*)features)[n * 32 + fc];
            float4 dv;
            dv.x = f.x - muv.x; dv.y = f.y - muv.y;
            dv.z = f.z - muv.z; dv.w = f.w - muv.w;
            *(float4*)&Dbuf[s16 * A_DIM + 4 * fc] = dv;
        }
        __syncthreads();
        // compute partial quadratic form
        if (s16 < m) {
            float4 p = {0.f, 0.f, 0.f, 0.f};
            #pragma unroll 4
            for (int i = 0; i < A_DIM; ++i) {
                const float  d = Dbuf[s16 * A_DIM + i];                  // broadcast
                const float4 a = *(const float4*)&As[i * LDSROW + 4 * fc]; // row-contig
                p.x += d * a.x; p.y += d * a.y; p.z += d * a.z; p.w += d * a.w;
            }
            const float4 dj = *(const float4*)&Dbuf[s16 * A_DIM + 4 * fc];
            Par[s16 * 33 + fc] = p.x * dj.x + p.y * dj.y + p.z * dj.z + p.w * dj.w;
        }
        __syncthreads();
        // reduce 32 partials per sample, write score
        if (tid < m) {
            const int n = idxg[cl * MAXPER + c0 + tid];
            float q = 0.f;
            #pragma unroll
            for (int j = 0; j < 32; ++j) q += Par[tid * 33 + j];
            score[n * K_CL + (bid & 3)] = q + ld;
        }
        __syncthreads();
    }
}

// ---------------------------------------------------------------------------
// Kernel 2: per (cl,k): gdiag[c]=W[c] S W[c]^T, gcol[c]=W[c] S W[cl]^T
// ---------------------------------------------------------------------------
__global__ __launch_bounds__(256) void k_gprep(
    const float* __restrict__ sigma, const float* __restrict__ weight,
    float* __restrict__ gdiag, float* __restrict__ gcol)
{
    __shared__ __align__(16) float Ss[A_DIM * A_DIM];   // 64 KB
    __shared__ __align__(16) float Ws[C_CLS * A_DIM];   // 51.2 KB
    const int tid = threadIdx.x, bid = blockIdx.x;
    const int cl  = bid >> 2;
    const int lane = tid & 63, wv = tid >> 6;

    const float4* src = (const float4*)(sigma + (size_t)bid * A_DIM * A_DIM);
    for (int e4 = tid; e4 < A_DIM * 32; e4 += 256)
        ((float4*)Ss)[e4] = src[e4];
    const float4* wsrc = (const float4*)weight;
    for (int e4 = tid; e4 < C_CLS * 32; e4 += 256)
        ((float4*)Ws)[e4] = wsrc[e4];
    __syncthreads();

    const float wc0 = Ws[cl * A_DIM + lane];
    const float wc1 = Ws[cl * A_DIM + 64 + lane];
    const int cbeg = wv * 25;               // 4 waves x 25 classes = 100

    for (int g = 0; g < 5; ++g) {           // 5 uniform groups of 5 rows
        const int c0 = cbeg + g * 5;
        const float* w0 = &Ws[(c0 + 0) * A_DIM];
        const float* w1 = &Ws[(c0 + 1) * A_DIM];
        const float* w2 = &Ws[(c0 + 2) * A_DIM];
        const float* w3 = &Ws[(c0 + 3) * A_DIM];
        const float* w4 = &Ws[(c0 + 4) * A_DIM];
        float h00 = 0.f, h01 = 0.f, h02 = 0.f, h03 = 0.f, h04 = 0.f;  // j = lane
        float h10 = 0.f, h11 = 0.f, h12 = 0.f, h13 = 0.f, h14 = 0.f;  // j = lane+64
        #pragma unroll 4
        for (int i = 0; i < A_DIM; ++i) {
            const float s0 = Ss[i * A_DIM + lane];
            const float s1 = Ss[i * A_DIM + 64 + lane];
            const float b0 = w0[i], b1 = w1[i], b2 = w2[i], b3 = w3[i], b4 = w4[i];
            h00 += b0 * s0; h10 += b0 * s1;
            h01 += b1 * s0; h11 += b1 * s1;
            h02 += b2 * s0; h12 += b2 * s1;
            h03 += b3 * s0; h13 += b3 * s1;
            h04 += b4 * s0; h14 += b4 * s1;
        }
        #define GOUT(HA, HB, CC)                                            \
        {                                                                   \
            const int c = c0 + (CC);                                        \
            float pd = (HA) * Ws[c * A_DIM + lane]                          \
                     + (HB) * Ws[c * A_DIM + 64 + lane];                    \
            float pc = (HA) * wc0 + (HB) * wc1;                             \
            _Pragma("unroll")                                               \
            for (int off = 32; off; off >>= 1) {                            \
                pd += __shfl_xor(pd, off, 64);                              \
                pc += __shfl_xor(pc, off, 64);                              \
            }                                                               \
            if (lane == 0) {                                                \
                gdiag[bid * C_CLS + c] = pd;                                \
                gcol [bid * C_CLS + c] = pc;                                \
            }                                                               \
        }
        GOUT(h00, h10, 0)
        GOUT(h01, h11, 1)
        GOUT(h02, h12, 2)
        GOUT(h03, h13, 3)
        GOUT(h04, h14, 4)
        #undef GOUT
    }
}

// ---------------------------------------------------------------------------
// Kernel 3 (fused fc + final)
// ---------------------------------------------------------------------------
__global__ __launch_bounds__(128) void k_out(
    const float* __restrict__ features, const float* __restrict__ weight,
    const float* __restrict__ bias, const int* __restrict__ labels,
    const float* __restrict__ score, const float* __restrict__ gdiag,
    const float* __restrict__ gcol, const float* __restrict__ ratio_p,
    float* __restrict__ y, float* __restrict__ loss)
{
    __shared__ __align__(16) float xs[A_DIM];
    __shared__ float red[2], red2[2], acl_s;
    const int n = blockIdx.x, t = threadIdx.x;
    xs[t] = features[(size_t)n * A_DIM + t];
    __syncthreads();

    const int cl = labels[n];
    const float ratio = *ratio_p;

    float s0 = score[n * 4 + 0], s1 = score[n * 4 + 1];
    float s2 = score[n * 4 + 2], s3 = score[n * 4 + 3];
    int ks = 0; float bs = s0;                   // strict <: first-min == jnp first-max
    if (s1 < bs) { bs = s1; ks = 1; }
    if (s2 < bs) { bs = s2; ks = 2; }
    if (s3 < bs) { bs = s3; ks = 3; }

    const int base = (cl * 4 + ks) * C_CLS;
    const float gll = gdiag[base + cl];
    float aug = -INFINITY;
    if (t < C_CLS) {
        const float4* wr = (const float4*)(weight + t * A_DIM);
        const float4* xr = (const float4*)xs;
        float acc = bias[t];
        #pragma unroll
        for (int j = 0; j < 32; ++j) {
            float4 a = xr[j], b = wr[j];
            acc += a.x * b.x + a.y * b.y + a.z * b.z + a.w * b.w;
        }
        y[(size_t)n * C_CLS + t] = acc;
        aug = acc + 0.5f * ratio * (gdiag[base + t] - 2.0f * gcol[base + t] + gll);
    }

    float m = aug;
    #pragma unroll
    for (int off = 32; off; off >>= 1) m = fmaxf(m, __shfl_xor(m, off, 64));
    if ((t & 63) == 0) red[t >> 6] = m;
    __syncthreads();
    m = fmaxf(red[0], red[1]);

    float e = (t < C_CLS) ? expf(aug - m) : 0.0f;
    #pragma unroll
    for (int off = 32; off; off >>= 1) e += __shfl_xor(e, off, 64);
    if ((t & 63) == 0) red2[t >> 6] = e;
    if (t == cl) acl_s = aug;
    __syncthreads();

    if (t == 0) {
        float sum = red2[0] + red2[1];
        float lp = acl_s - m - logf(sum);
        atomicAdd(loss, -lp * (1.0f / (float)N_S));
    }
}

// ---------------------------------------------------------------------------
extern "C" void kernel_launch(void* const* d_in, const int* in_sizes, int n_in,
                              void* d_out, int out_size, void* d_ws, size_t ws_size,
                              hipStream_t stream) {
    const float* features = (const float*)d_in[0];
    const float* weight   = (const float*)d_in[1];
    const float* bias     = (const float*)d_in[2];
    // d_in[3] = pi : unused (q is one-hot for any pi > 0; argmax unaffected)
    const float* mu       = (const float*)d_in[4];
    const float* sigma    = (const float*)d_in[5];
    const int*   labels   = (const int*)d_in[6];
    const float* ratio    = (const float*)d_in[7];

    float* out   = (float*)d_out;   // [0] = loss, [1..204800] = y
    float* yout  = out + 1;
    float* score = (float*)d_ws;                  // 8192 f32
    float* gdiag = score + N_S * K_CL;            // 40000 f32
    float* gcol  = gdiag + C_CLS * K_CL * C_CLS;  // 40000 f32
    int*   cntg  = (int*)(gcol + C_CLS * K_CL * C_CLS);  // 100 int
    int*   idxg  = cntg + C_CLS;                          // 9600 int

    hipMemsetAsync(d_out, 0, sizeof(float), stream);   // zero the loss accumulator

    k_bucket      <<<dim3(1),            dim3(256), 0, stream>>>(labels, cntg, idxg);
    k_invert_score<<<dim3(C_CLS * K_CL), dim3(512), 0, stream>>>(sigma, mu, features,
                                                                 cntg, idxg, score);
    k_gprep       <<<dim3(C_CLS * K_CL), dim3(256), 0, stream>>>(sigma, weight, gdiag, gcol);
    k_out         <<<dim3(N_S),          dim3(128), 0, stream>>>(features, weight, bias, labels,
                                                                 score, gdiag, gcol, ratio, yout, out);
}

// Round 11
// 218.510 us; speedup vs baseline: 1.9720x; 1.1583x over previous
//
#include <hip/hip_runtime.h>
#include <hip/hip_bf16.h>
#include <cmath>

#define N_S    2048
#define C_CLS  100
#define K_CL   4
#define A_DIM  128
#define LDSROW 132   // padded row stride: breaks row-power-of-2 bank aliasing
#define NB     16    // GJ panel width
#define MAXPER 96    // max samples per class (mean 20.5; >15 sigma headroom)
#define WTPAD  101   // k_out transposed-W stride (reads conflict-free)
#define SPB    8     // samples per k_out block (256 blocks)

// ---------------------------------------------------------------------------
// Kernel 0: bucket samples by class
// ---------------------------------------------------------------------------
__global__ __launch_bounds__(256) void k_bucket(
    const int* __restrict__ labels, int* __restrict__ cntg, int* __restrict__ idxg)
{
    __shared__ int cntL[C_CLS];
    const int t = threadIdx.x;
    if (t < C_CLS) cntL[t] = 0;
    __syncthreads();
    for (int n = t; n < N_S; n += 256) {
        int c = labels[n];
        int slot = atomicAdd(&cntL[c], 1);
        if (slot < MAXPER) idxg[c * MAXPER + slot] = n;
    }
    __syncthreads();
    if (t < C_CLS) cntg[t] = min(cntL[t], MAXPER);
}

// ===========================================================================
// Blocked Gauss-Jordan of As (in LDS), returns logdet in wave 0's lanes.
// (unchanged — round-10 passing version)
// ===========================================================================
__device__ __forceinline__ float gj_invert_lds(
    float* As, float* Rbuf, float* DinvS, int tid)
{
    const int lane = tid & 63;
    const int wv   = tid >> 6;
    float logdet = 0.0f;                 // valid in wave 0 only

    for (int t = 0; t < 8; ++t) {
        const int p0 = NB * t;

        // (a) wave 0: invert 16x16 diagonal block in registers (shfl GJ)
        if (wv == 0) {
            const int r = lane >> 2, cg = lane & 3;
            float4 dv = *(const float4*)&As[(p0 + r) * LDSROW + p0 + 4 * cg];
            #pragma unroll
            for (int p = 0; p < NB; ++p) {
                const int sel = p & 3, pr4 = p >> 2;
                float te = (sel == 0) ? dv.x : (sel == 1) ? dv.y : (sel == 2) ? dv.z : dv.w;
                float piv = __shfl(te, (p << 2) | pr4, 64);
                float ip  = 1.0f / piv;
                logdet += __logf(piv);
                const int rowsrc = (p << 2) | cg;
                float4 prs;
                prs.x = __shfl(dv.x, rowsrc, 64) * ip;
                prs.y = __shfl(dv.y, rowsrc, 64) * ip;
                prs.z = __shfl(dv.z, rowsrc, 64) * ip;
                prs.w = __shfl(dv.w, rowsrc, 64) * ip;
                if (cg == pr4) (&prs.x)[sel] = ip;           // (p,p) -> 1/piv
                float f = __shfl(te, (lane & ~3) | pr4, 64); // my row's col-p value
                if (r == p) {
                    dv = prs;
                } else {
                    dv.x -= f * prs.x; dv.y -= f * prs.y;
                    dv.z -= f * prs.z; dv.w -= f * prs.w;
                    if (cg == pr4) (&dv.x)[sel] = -f * ip;   // col p: assign
                }
            }
            DinvS[r * 17 + 4 * cg + 0] = dv.x;
            DinvS[r * 17 + 4 * cg + 1] = dv.y;
            DinvS[r * 17 + 4 * cg + 2] = dv.z;
            DinvS[r * 17 + 4 * cg + 3] = dv.w;
        }
        __syncthreads();   // b1: Dinv ready

        // (b) Rnew = Dinv * A[P,:] into Rbuf; panel cols get Dinv itself.
        {
            const int rr = tid >> 5, j4c = tid & 31;
            float4 o;
            if ((j4c >> 2) == t) {
                const int cg = j4c & 3;
                o.x = DinvS[rr * 17 + 4 * cg + 0];
                o.y = DinvS[rr * 17 + 4 * cg + 1];
                o.z = DinvS[rr * 17 + 4 * cg + 2];
                o.w = DinvS[rr * 17 + 4 * cg + 3];
            } else {
                o.x = 0.f; o.y = 0.f; o.z = 0.f; o.w = 0.f;
                #pragma unroll 4
                for (int k = 0; k < NB; ++k) {
                    const float a = DinvS[rr * 17 + k];          // broadcast
                    const float4 s4 = *(const float4*)&As[(p0 + k) * LDSROW + 4 * j4c];
                    o.x += a * s4.x; o.y += a * s4.y; o.z += a * s4.z; o.w += a * s4.w;
                }
            }
            *(float4*)&Rbuf[rr * A_DIM + 4 * j4c] = o;
        }
        __syncthreads();   // b2: Rnew ready (As panel rows still OLD)

        // (c) rank-16 update of 112 non-panel rows: per thread 4 rows x 8 cols.
        if (tid < 448) {
            const int rgi = tid >> 4;                 // 0..27 non-panel row group
            const int cp  = tid & 15;                 // j4 pair
            const int rga = (rgi < 4 * t) ? rgi : rgi + 4;
            const int row0 = 4 * rga;
            const int c0 = 8 * cp, c1 = 8 * cp + 4;
            const bool pcol = ((cp >> 1) == t);       // my 2 j4s are the panel cols
            float4 a00, a01, a10, a11, a20, a21, a30, a31;
            if (pcol) {
                a00 = a01 = a10 = a11 = a20 = a21 = a30 = a31 = (float4){0, 0, 0, 0};
            } else {
                a00 = *(const float4*)&As[(row0 + 0) * LDSROW + c0];
                a01 = *(const float4*)&As[(row0 + 0) * LDSROW + c1];
                a10 = *(const float4*)&As[(row0 + 1) * LDSROW + c0];
                a11 = *(const float4*)&As[(row0 + 1) * LDSROW + c1];
                a20 = *(const float4*)&As[(row0 + 2) * LDSROW + c0];
                a21 = *(const float4*)&As[(row0 + 2) * LDSROW + c1];
                a30 = *(const float4*)&As[(row0 + 3) * LDSROW + c0];
                a31 = *(const float4*)&As[(row0 + 3) * LDSROW + c1];
            }
            #pragma unroll 4
            for (int k = 0; k < NB; ++k) {
                const float4 r0 = *(const float4*)&Rbuf[k * A_DIM + c0];
                const float4 r1 = *(const float4*)&Rbuf[k * A_DIM + c1];
                const float f0 = As[(row0 + 0) * LDSROW + p0 + k];
                const float f1 = As[(row0 + 1) * LDSROW + p0 + k];
                const float f2 = As[(row0 + 2) * LDSROW + p0 + k];
                const float f3 = As[(row0 + 3) * LDSROW + p0 + k];
                a00.x -= f0 * r0.x; a00.y -= f0 * r0.y; a00.z -= f0 * r0.z; a00.w -= f0 * r0.w;
                a01.x -= f0 * r1.x; a01.y -= f0 * r1.y; a01.z -= f0 * r1.z; a01.w -= f0 * r1.w;
                a10.x -= f1 * r0.x; a10.y -= f1 * r0.y; a10.z -= f1 * r0.z; a10.w -= f1 * r0.w;
                a11.x -= f1 * r1.x; a11.y -= f1 * r1.y; a11.z -= f1 * r1.z; a11.w -= f1 * r1.w;
                a20.x -= f2 * r0.x; a20.y -= f2 * r0.y; a20.z -= f2 * r0.z; a20.w -= f2 * r0.w;
                a21.x -= f2 * r1.x; a21.y -= f2 * r1.y; a21.z -= f2 * r1.z; a21.w -= f2 * r1.w;
                a30.x -= f3 * r0.x; a30.y -= f3 * r0.y; a30.z -= f3 * r0.z; a30.w -= f3 * r0.w;
                a31.x -= f3 * r1.x; a31.y -= f3 * r1.y; a31.z -= f3 * r1.z; a31.w -= f3 * r1.w;
            }
            *(float4*)&As[(row0 + 0) * LDSROW + c0] = a00;
            *(float4*)&As[(row0 + 0) * LDSROW + c1] = a01;
            *(float4*)&As[(row0 + 1) * LDSROW + c0] = a10;
            *(float4*)&As[(row0 + 1) * LDSROW + c1] = a11;
            *(float4*)&As[(row0 + 2) * LDSROW + c0] = a20;
            *(float4*)&As[(row0 + 2) * LDSROW + c1] = a21;
            *(float4*)&As[(row0 + 3) * LDSROW + c0] = a30;
            *(float4*)&As[(row0 + 3) * LDSROW + c1] = a31;
        }
        // copyback Rbuf -> As panel rows (panel rows untouched by the update)
        {
            const int rr = tid >> 5, j4c = tid & 31;
            *(float4*)&As[(p0 + rr) * LDSROW + 4 * j4c] =
                *(const float4*)&Rbuf[rr * A_DIM + 4 * j4c];
        }
        __syncthreads();   // b3: panel done
    }
    return logdet;
}

// ---------------------------------------------------------------------------
// Kernel 1 (unchanged round-10): GJ invert + batched score tail.
// ---------------------------------------------------------------------------
__global__ __launch_bounds__(512, 2) void k_invert_score(
    const float* __restrict__ sigma, const float* __restrict__ mu,
    const float* __restrict__ features, const int* __restrict__ cntg,
    const int* __restrict__ idxg, float* __restrict__ score)
{
    __shared__ __align__(16) float As[A_DIM * LDSROW];          // 67.6 KB
    __shared__ __align__(16) float Scratch[NB * A_DIM + 16*33]; // Rbuf / Dbuf+Par
    __shared__ float DinvS[NB * 17];
    __shared__ float ldS;

    const int tid = threadIdx.x;
    const int bid = blockIdx.x;          // cl*K_CL + k
    const int cl  = bid >> 2;

    const float4* src = (const float4*)(sigma + (size_t)bid * A_DIM * A_DIM);
    for (int e4 = tid; e4 < A_DIM * 32; e4 += 512) {
        int i = e4 >> 5, j4 = e4 & 31;
        *(float4*)&As[i * LDSROW + 4 * j4] = src[e4];
    }
    __syncthreads();

    float logdet = gj_invert_lds(As, Scratch, DinvS, tid);
    if (tid == 0) ldS = logdet;
    __syncthreads();
    const float ld = ldS;
    // As = Sigma^{-1}

    float* Dbuf = Scratch;                  // [16][128]
    float* Par  = Scratch + NB * A_DIM;     // [16][33] padded
    const int s16 = tid >> 5;               // sample slot 0..15
    const int fc  = tid & 31;               // float4 column 0..31
    const int cnt = cntg[cl];
    const float4 muv = ((const float4*)mu)[bid * 32 + fc];

    for (int c0 = 0; c0 < cnt; c0 += 16) {
        const int m = cnt - c0 < 16 ? cnt - c0 : 16;
        if (s16 < m) {
            const int n = idxg[cl * MAXPER + c0 + s16];
            const float4 f = ((const float4*)features)[n * 32 + fc];
            float4 dv;
            dv.x = f.x - muv.x; dv.y = f.y - muv.y;
            dv.z = f.z - muv.z; dv.w = f.w - muv.w;
            *(float4*)&Dbuf[s16 * A_DIM + 4 * fc] = dv;
        }
        __syncthreads();
        if (s16 < m) {
            float4 p = {0.f, 0.f, 0.f, 0.f};
            #pragma unroll 4
            for (int i = 0; i < A_DIM; ++i) {
                const float  d = Dbuf[s16 * A_DIM + i];                    // broadcast
                const float4 a = *(const float4*)&As[i * LDSROW + 4 * fc]; // row-contig
                p.x += d * a.x; p.y += d * a.y; p.z += d * a.z; p.w += d * a.w;
            }
            const float4 dj = *(const float4*)&Dbuf[s16 * A_DIM + 4 * fc];
            Par[s16 * 33 + fc] = p.x * dj.x + p.y * dj.y + p.z * dj.z + p.w * dj.w;
        }
        __syncthreads();
        if (tid < m) {
            const int n = idxg[cl * MAXPER + c0 + tid];
            float q = 0.f;
            #pragma unroll
            for (int j = 0; j < 32; ++j) q += Par[tid * 33 + j];
            score[n * K_CL + (bid & 3)] = q + ld;
        }
        __syncthreads();
    }
}

// ---------------------------------------------------------------------------
// Kernel 2 (REWRITTEN): gdiag[c]=W[c] S W[c]^T, gcol[c]=W[c] S W[cl]^T.
// Changes vs round-5 version: (1) W rows read via readfirstlane-uniform
// SGPR loads (s_load; off the LDS pipe) instead of a 51KB LDS stage ->
// LDS = 64KB Sigma only -> 2 blocks/CU; (2) 10-row sweeps (20 static-index
// accumulators) halve Sigma re-reads: 20 -> 12 sweeps per block.
// ---------------------------------------------------------------------------
template<int R>
__device__ __forceinline__ void gsweep(
    const float* __restrict__ Ss, const float* __restrict__ weight,
    int c0, int lane, float wc0, float wc1, int bid,
    float* __restrict__ gdiag, float* __restrict__ gcol)
{
    const int c0u = __builtin_amdgcn_readfirstlane(c0);
    const float* __restrict__ wr = weight + (size_t)c0u * A_DIM;  // uniform base
    float h0[R], h1[R];
    #pragma unroll
    for (int r = 0; r < R; ++r) { h0[r] = 0.f; h1[r] = 0.f; }
    #pragma unroll 2
    for (int i = 0; i < A_DIM; ++i) {
        const float s0 = Ss[i * A_DIM + lane];        // conflict-free
        const float s1 = Ss[i * A_DIM + 64 + lane];
        #pragma unroll
        for (int r = 0; r < R; ++r) {
            const float b = wr[r * A_DIM + i];        // uniform -> scalar load
            h0[r] += b * s0; h1[r] += b * s1;
        }
    }
    #pragma unroll
    for (int r = 0; r < R; ++r) {
        const int c = c0 + r;
        float pd = h0[r] * weight[c * A_DIM + lane]
                 + h1[r] * weight[c * A_DIM + 64 + lane];
        float pc = h0[r] * wc0 + h1[r] * wc1;
        #pragma unroll
        for (int off = 32; off; off >>= 1) {
            pd += __shfl_xor(pd, off, 64);
            pc += __shfl_xor(pc, off, 64);
        }
        if (lane == 0) {
            gdiag[bid * C_CLS + c] = pd;
            gcol [bid * C_CLS + c] = pc;
        }
    }
}

__global__ __launch_bounds__(256, 2) void k_gprep(
    const float* __restrict__ sigma, const float* __restrict__ weight,
    float* __restrict__ gdiag, float* __restrict__ gcol)
{
    __shared__ __align__(16) float Ss[A_DIM * A_DIM];   // 64 KB (only)
    const int tid = threadIdx.x, bid = blockIdx.x;
    const int cl  = bid >> 2;
    const int lane = tid & 63, wv = tid >> 6;

    const float4* src = (const float4*)(sigma + (size_t)bid * A_DIM * A_DIM);
    for (int e4 = tid; e4 < A_DIM * 32; e4 += 256)
        ((float4*)Ss)[e4] = src[e4];
    __syncthreads();

    const float wc0 = weight[cl * A_DIM + lane];
    const float wc1 = weight[cl * A_DIM + 64 + lane];
    const int cbeg = wv * 25;               // 4 waves x 25 classes

    gsweep<10>(Ss, weight, cbeg,      lane, wc0, wc1, bid, gdiag, gcol);
    gsweep<10>(Ss, weight, cbeg + 10, lane, wc0, wc1, bid, gdiag, gcol);
    gsweep<5> (Ss, weight, cbeg + 20, lane, wc0, wc1, bid, gdiag, gcol);
}

// ---------------------------------------------------------------------------
// Kernel 3 (REWRITTEN): 256 blocks x 8 samples. W staged TRANSPOSED in LDS
// (stride 101: reads Wt[j*101+t] consecutive -> conflict-free; replaces the
// per-block 51KB global W re-read). 2 samples concurrently (128-thr halves).
// Loss accumulated in LDS, one global atomic per block (2048 -> 256).
// ---------------------------------------------------------------------------
__global__ __launch_bounds__(256) void k_out(
    const float* __restrict__ features, const float* __restrict__ weight,
    const float* __restrict__ bias, const int* __restrict__ labels,
    const float* __restrict__ score, const float* __restrict__ gdiag,
    const float* __restrict__ gcol, const float* __restrict__ ratio_p,
    float* __restrict__ y, float* __restrict__ loss)
{
    __shared__ float Wt[A_DIM * WTPAD];     // 51.7 KB transposed W
    __shared__ float bs[C_CLS];
    __shared__ __align__(16) float xs[2][A_DIM];
    __shared__ float red[2][2], red2[2][2], acl_s[2], lsum;

    const int tid  = threadIdx.x;
    const int half = tid >> 7;              // which sample of the pair
    const int t    = tid & 127;

    // stage W transposed (one-time; 4-way write conflicts acceptable)
    for (int u = tid; u < C_CLS * 32; u += 256) {
        const int c = u >> 5, j4 = u & 31;
        const float4 w = ((const float4*)weight)[u];
        Wt[(4 * j4 + 0) * WTPAD + c] = w.x;
        Wt[(4 * j4 + 1) * WTPAD + c] = w.y;
        Wt[(4 * j4 + 2) * WTPAD + c] = w.z;
        Wt[(4 * j4 + 3) * WTPAD + c] = w.w;
    }
    if (tid < C_CLS) bs[tid] = bias[tid];
    if (tid == 0) lsum = 0.f;
    __syncthreads();

    const float ratio = *ratio_p;

    for (int p = 0; p < SPB; p += 2) {
        const int n = blockIdx.x * SPB + p + half;
        if (t < 32) ((float4*)xs[half])[t] = ((const float4*)features)[n * 32 + t];
        __syncthreads();

        const int cl = labels[n];
        float s0 = score[n * 4 + 0], s1 = score[n * 4 + 1];
        float s2 = score[n * 4 + 2], s3 = score[n * 4 + 3];
        int ks = 0; float bsv = s0;              // strict <: first-min == jnp first-max
        if (s1 < bsv) { bsv = s1; ks = 1; }
        if (s2 < bsv) { bsv = s2; ks = 2; }
        if (s3 < bsv) { bsv = s3; ks = 3; }

        const int base = (cl * 4 + ks) * C_CLS;
        const float gll = gdiag[base + cl];
        float aug = -INFINITY;
        if (t < C_CLS) {
            float acc = bs[t];
            #pragma unroll 4
            for (int j = 0; j < A_DIM; ++j)
                acc += xs[half][j] * Wt[j * WTPAD + t];   // broadcast x conflict-free
            y[(size_t)n * C_CLS + t] = acc;
            aug = acc + 0.5f * ratio * (gdiag[base + t] - 2.0f * gcol[base + t] + gll);
        }

        float m = aug;
        #pragma unroll
        for (int off = 32; off; off >>= 1) m = fmaxf(m, __shfl_xor(m, off, 64));
        if ((t & 63) == 0) red[half][t >> 6] = m;
        __syncthreads();
        m = fmaxf(red[half][0], red[half][1]);

        float e = (t < C_CLS) ? expf(aug - m) : 0.0f;
        #pragma unroll
        for (int off = 32; off; off >>= 1) e += __shfl_xor(e, off, 64);
        if ((t & 63) == 0) red2[half][t >> 6] = e;
        if (t == cl) acl_s[half] = aug;
        __syncthreads();

        if (t == 0) {
            float lp = acl_s[half] - m - logf(red2[half][0] + red2[half][1]);
            atomicAdd(&lsum, -lp);
        }
        __syncthreads();    // protect xs/red before next pair
    }
    if (tid == 0) atomicAdd(loss, lsum * (1.0f / (float)N_S));
}

// ---------------------------------------------------------------------------
extern "C" void kernel_launch(void* const* d_in, const int* in_sizes, int n_in,
                              void* d_out, int out_size, void* d_ws, size_t ws_size,
                              hipStream_t stream) {
    const float* features = (const float*)d_in[0];
    const float* weight   = (const float*)d_in[1];
    const float* bias     = (const float*)d_in[2];
    // d_in[3] = pi : unused (q is one-hot for any pi > 0; argmax unaffected)
    const float* mu       = (const float*)d_in[4];
    const float* sigma    = (const float*)d_in[5];
    const int*   labels   = (const int*)d_in[6];
    const float* ratio    = (const float*)d_in[7];

    float* out   = (float*)d_out;   // [0] = loss, [1..204800] = y
    float* yout  = out + 1;
    float* score = (float*)d_ws;                  // 8192 f32
    float* gdiag = score + N_S * K_CL;            // 40000 f32
    float* gcol  = gdiag + C_CLS * K_CL * C_CLS;  // 40000 f32
    int*   cntg  = (int*)(gcol + C_CLS * K_CL * C_CLS);  // 100 int
    int*   idxg  = cntg + C_CLS;                          // 9600 int

    hipMemsetAsync(d_out, 0, sizeof(float), stream);   // zero the loss accumulator

    k_bucket      <<<dim3(1),            dim3(256), 0, stream>>>(labels, cntg, idxg);
    k_invert_score<<<dim3(C_CLS * K_CL), dim3(512), 0, stream>>>(sigma, mu, features,
                                                                 cntg, idxg, score);
    k_gprep       <<<dim3(C_CLS * K_CL), dim3(256), 0, stream>>>(sigma, weight, gdiag, gcol);
    k_out         <<<dim3(N_S / SPB),    dim3(256), 0, stream>>>(features, weight, bias, labels,
                                                                 score, gdiag, gcol, ratio, yout, out);
}

// Round 12
// 210.516 us; speedup vs baseline: 2.0469x; 1.0380x over previous
//
#include <hip/hip_runtime.h>
#include <hip/hip_bf16.h>
#include <cmath>

#define N_S    2048
#define C_CLS  100
#define K_CL   4
#define A_DIM  128
#define LDSROW 132   // padded row stride: breaks row-power-of-2 bank aliasing
#define NB     16    // GJ panel width
#define MAXPER 96    // max samples per class (mean 20.5; >15 sigma headroom)
#define WTPAD  101   // k_out transposed-W stride (reads conflict-free)
#define SPB    8     // samples per k_out block (256 blocks)

// ===========================================================================
// Blocked Gauss-Jordan of As (in LDS), returns logdet in wave 0's lanes.
// (unchanged — rounds 10/11 passing version)
// ===========================================================================
__device__ __forceinline__ float gj_invert_lds(
    float* As, float* Rbuf, float* DinvS, int tid)
{
    const int lane = tid & 63;
    const int wv   = tid >> 6;
    float logdet = 0.0f;                 // valid in wave 0 only

    for (int t = 0; t < 8; ++t) {
        const int p0 = NB * t;

        // (a) wave 0: invert 16x16 diagonal block in registers (shfl GJ)
        if (wv == 0) {
            const int r = lane >> 2, cg = lane & 3;
            float4 dv = *(const float4*)&As[(p0 + r) * LDSROW + p0 + 4 * cg];
            #pragma unroll
            for (int p = 0; p < NB; ++p) {
                const int sel = p & 3, pr4 = p >> 2;
                float te = (sel == 0) ? dv.x : (sel == 1) ? dv.y : (sel == 2) ? dv.z : dv.w;
                float piv = __shfl(te, (p << 2) | pr4, 64);
                float ip  = 1.0f / piv;
                logdet += __logf(piv);
                const int rowsrc = (p << 2) | cg;
                float4 prs;
                prs.x = __shfl(dv.x, rowsrc, 64) * ip;
                prs.y = __shfl(dv.y, rowsrc, 64) * ip;
                prs.z = __shfl(dv.z, rowsrc, 64) * ip;
                prs.w = __shfl(dv.w, rowsrc, 64) * ip;
                if (cg == pr4) (&prs.x)[sel] = ip;           // (p,p) -> 1/piv
                float f = __shfl(te, (lane & ~3) | pr4, 64); // my row's col-p value
                if (r == p) {
                    dv = prs;
                } else {
                    dv.x -= f * prs.x; dv.y -= f * prs.y;
                    dv.z -= f * prs.z; dv.w -= f * prs.w;
                    if (cg == pr4) (&dv.x)[sel] = -f * ip;   // col p: assign
                }
            }
            DinvS[r * 17 + 4 * cg + 0] = dv.x;
            DinvS[r * 17 + 4 * cg + 1] = dv.y;
            DinvS[r * 17 + 4 * cg + 2] = dv.z;
            DinvS[r * 17 + 4 * cg + 3] = dv.w;
        }
        __syncthreads();   // b1: Dinv ready

        // (b) Rnew = Dinv * A[P,:] into Rbuf; panel cols get Dinv itself.
        {
            const int rr = tid >> 5, j4c = tid & 31;
            float4 o;
            if ((j4c >> 2) == t) {
                const int cg = j4c & 3;
                o.x = DinvS[rr * 17 + 4 * cg + 0];
                o.y = DinvS[rr * 17 + 4 * cg + 1];
                o.z = DinvS[rr * 17 + 4 * cg + 2];
                o.w = DinvS[rr * 17 + 4 * cg + 3];
            } else {
                o.x = 0.f; o.y = 0.f; o.z = 0.f; o.w = 0.f;
                #pragma unroll 4
                for (int k = 0; k < NB; ++k) {
                    const float a = DinvS[rr * 17 + k];          // broadcast
                    const float4 s4 = *(const float4*)&As[(p0 + k) * LDSROW + 4 * j4c];
                    o.x += a * s4.x; o.y += a * s4.y; o.z += a * s4.z; o.w += a * s4.w;
                }
            }
            *(float4*)&Rbuf[rr * A_DIM + 4 * j4c] = o;
        }
        __syncthreads();   // b2: Rnew ready (As panel rows still OLD)

        // (c) rank-16 update of 112 non-panel rows: per thread 4 rows x 8 cols.
        if (tid < 448) {
            const int rgi = tid >> 4;                 // 0..27 non-panel row group
            const int cp  = tid & 15;                 // j4 pair
            const int rga = (rgi < 4 * t) ? rgi : rgi + 4;
            const int row0 = 4 * rga;
            const int c0 = 8 * cp, c1 = 8 * cp + 4;
            const bool pcol = ((cp >> 1) == t);       // my 2 j4s are the panel cols
            float4 a00, a01, a10, a11, a20, a21, a30, a31;
            if (pcol) {
                a00 = a01 = a10 = a11 = a20 = a21 = a30 = a31 = (float4){0, 0, 0, 0};
            } else {
                a00 = *(const float4*)&As[(row0 + 0) * LDSROW + c0];
                a01 = *(const float4*)&As[(row0 + 0) * LDSROW + c1];
                a10 = *(const float4*)&As[(row0 + 1) * LDSROW + c0];
                a11 = *(const float4*)&As[(row0 + 1) * LDSROW + c1];
                a20 = *(const float4*)&As[(row0 + 2) * LDSROW + c0];
                a21 = *(const float4*)&As[(row0 + 2) * LDSROW + c1];
                a30 = *(const float4*)&As[(row0 + 3) * LDSROW + c0];
                a31 = *(const float4*)&As[(row0 + 3) * LDSROW + c1];
            }
            #pragma unroll 4
            for (int k = 0; k < NB; ++k) {
                const float4 r0 = *(const float4*)&Rbuf[k * A_DIM + c0];
                const float4 r1 = *(const float4*)&Rbuf[k * A_DIM + c1];
                const float f0 = As[(row0 + 0) * LDSROW + p0 + k];
                const float f1 = As[(row0 + 1) * LDSROW + p0 + k];
                const float f2 = As[(row0 + 2) * LDSROW + p0 + k];
                const float f3 = As[(row0 + 3) * LDSROW + p0 + k];
                a00.x -= f0 * r0.x; a00.y -= f0 * r0.y; a00.z -= f0 * r0.z; a00.w -= f0 * r0.w;
                a01.x -= f0 * r1.x; a01.y -= f0 * r1.y; a01.z -= f0 * r1.z; a01.w -= f0 * r1.w;
                a10.x -= f1 * r0.x; a10.y -= f1 * r0.y; a10.z -= f1 * r0.z; a10.w -= f1 * r0.w;
                a11.x -= f1 * r1.x; a11.y -= f1 * r1.y; a11.z -= f1 * r1.z; a11.w -= f1 * r1.w;
                a20.x -= f2 * r0.x; a20.y -= f2 * r0.y; a20.z -= f2 * r0.z; a20.w -= f2 * r0.w;
                a21.x -= f2 * r1.x; a21.y -= f2 * r1.y; a21.z -= f2 * r1.z; a21.w -= f2 * r1.w;
                a30.x -= f3 * r0.x; a30.y -= f3 * r0.y; a30.z -= f3 * r0.z; a30.w -= f3 * r0.w;
                a31.x -= f3 * r1.x; a31.y -= f3 * r1.y; a31.z -= f3 * r1.z; a31.w -= f3 * r1.w;
            }
            *(float4*)&As[(row0 + 0) * LDSROW + c0] = a00;
            *(float4*)&As[(row0 + 0) * LDSROW + c1] = a01;
            *(float4*)&As[(row0 + 1) * LDSROW + c0] = a10;
            *(float4*)&As[(row0 + 1) * LDSROW + c1] = a11;
            *(float4*)&As[(row0 + 2) * LDSROW + c0] = a20;
            *(float4*)&As[(row0 + 2) * LDSROW + c1] = a21;
            *(float4*)&As[(row0 + 3) * LDSROW + c0] = a30;
            *(float4*)&As[(row0 + 3) * LDSROW + c1] = a31;
        }
        // copyback Rbuf -> As panel rows (panel rows untouched by the update)
        {
            const int rr = tid >> 5, j4c = tid & 31;
            *(float4*)&As[(p0 + rr) * LDSROW + 4 * j4c] =
                *(const float4*)&Rbuf[rr * A_DIM + 4 * j4c];
        }
        __syncthreads();   // b3: panel done
    }
    return logdet;
}

// ---------------------------------------------------------------------------
// gprep sweep reading the PADDED As (sigma, pre-inversion). Per-r row index
// clamped + readfirstlane-uniform -> scalar loads. Static-index arrays only.
// ---------------------------------------------------------------------------
template<int R>
__device__ __forceinline__ void gsweep(
    const float* __restrict__ As, const float* __restrict__ weight,
    int c0, int lane, float wc0, float wc1, int bid,
    float* __restrict__ gdiag, float* __restrict__ gcol)
{
    const int c0u = __builtin_amdgcn_readfirstlane(c0);
    const float* wr[R];
    #pragma unroll
    for (int r = 0; r < R; ++r) {
        int c = c0u + r; c = (c < C_CLS) ? c : (C_CLS - 1);
        wr[r] = weight + (size_t)c * A_DIM;          // uniform base
    }
    float h0[R], h1[R];
    #pragma unroll
    for (int r = 0; r < R; ++r) { h0[r] = 0.f; h1[r] = 0.f; }
    #pragma unroll 2
    for (int i = 0; i < A_DIM; ++i) {
        const float s0 = As[i * LDSROW + lane];       // conflict-free
        const float s1 = As[i * LDSROW + 64 + lane];
        #pragma unroll
        for (int r = 0; r < R; ++r) {
            const float b = wr[r][i];                 // uniform -> scalar load
            h0[r] += b * s0; h1[r] += b * s1;
        }
    }
    #pragma unroll
    for (int r = 0; r < R; ++r) {
        const int c = c0 + r;
        if (c < C_CLS) {
            float pd = h0[r] * weight[c * A_DIM + lane]
                     + h1[r] * weight[c * A_DIM + 64 + lane];
            float pc = h0[r] * wc0 + h1[r] * wc1;
            #pragma unroll
            for (int off = 32; off; off >>= 1) {
                pd += __shfl_xor(pd, off, 64);
                pc += __shfl_xor(pc, off, 64);
            }
            if (lane == 0) {
                gdiag[bid * C_CLS + c] = pd;
                gcol [bid * C_CLS + c] = pc;
            }
        }
    }
}

// ---------------------------------------------------------------------------
// Kernel 1 (FUSED): stage sigma -> [bucket scan + gprep on resident sigma]
// -> blocked GJ inversion -> batched score tail. Replaces the former
// k_bucket + k_invert_score + k_gprep (3 dispatches -> 1; sigma read once).
// ---------------------------------------------------------------------------
__global__ __launch_bounds__(512, 2) void k_fused(
    const float* __restrict__ sigma, const float* __restrict__ mu,
    const float* __restrict__ features, const int* __restrict__ labels,
    const float* __restrict__ weight, float* __restrict__ score,
    float* __restrict__ gdiag, float* __restrict__ gcol)
{
    __shared__ __align__(16) float As[A_DIM * LDSROW];          // 67.6 KB
    __shared__ __align__(16) float Scratch[NB * A_DIM + 16*33]; // Rbuf / Dbuf+Par
    __shared__ float DinvS[NB * 17];
    __shared__ float ldS;
    __shared__ int idxL[MAXPER];
    __shared__ int cntA;

    const int tid  = threadIdx.x;
    const int bid  = blockIdx.x;         // cl*K_CL + k
    const int cl   = bid >> 2;
    const int lane = tid & 63;
    const int wv   = tid >> 6;

    if (tid == 0) cntA = 0;

    // ---- stage sigma (coalesced b128) ----
    const float4* src = (const float4*)(sigma + (size_t)bid * A_DIM * A_DIM);
    for (int e4 = tid; e4 < A_DIM * 32; e4 += 512) {
        int i = e4 >> 5, j4 = e4 & 31;
        *(float4*)&As[i * LDSROW + 4 * j4] = src[e4];
    }
    __syncthreads();

    // ---- bucket scan (replaces k_bucket; labels are L2-resident 8KB) ----
    for (int n = tid; n < N_S; n += 512) {
        if (labels[n] == cl) {
            int s = atomicAdd(&cntA, 1);
            if (s < MAXPER) idxL[s] = n;
        }
    }
    // ---- gprep on resident sigma (replaces k_gprep; 8 waves x 13 classes) ----
    {
        const float wc0 = weight[cl * A_DIM + lane];
        const float wc1 = weight[cl * A_DIM + 64 + lane];
        gsweep<13>(As, weight, wv * 13, lane, wc0, wc1, bid, gdiag, gcol);
    }
    __syncthreads();   // gprep/scan reads done before GJ overwrites As

    float logdet = gj_invert_lds(As, Scratch, DinvS, tid);
    if (tid == 0) ldS = logdet;
    __syncthreads();
    const float ld = ldS;
    const int cnt = min(cntA, MAXPER);
    // As = Sigma^{-1}

    // ---- batched per-sample quadratic form (unchanged round-10 tail) ----
    float* Dbuf = Scratch;                  // [16][128]
    float* Par  = Scratch + NB * A_DIM;     // [16][33] padded
    const int s16 = tid >> 5;               // sample slot 0..15
    const int fc  = tid & 31;               // float4 column 0..31
    const float4 muv = ((const float4*)mu)[bid * 32 + fc];

    for (int c0 = 0; c0 < cnt; c0 += 16) {
        const int m = cnt - c0 < 16 ? cnt - c0 : 16;
        if (s16 < m) {
            const int n = idxL[c0 + s16];
            const float4 f = ((const float4*)features)[n * 32 + fc];
            float4 dv;
            dv.x = f.x - muv.x; dv.y = f.y - muv.y;
            dv.z = f.z - muv.z; dv.w = f.w - muv.w;
            *(float4*)&Dbuf[s16 * A_DIM + 4 * fc] = dv;
        }
        __syncthreads();
        if (s16 < m) {
            float4 p = {0.f, 0.f, 0.f, 0.f};
            #pragma unroll 4
            for (int i = 0; i < A_DIM; ++i) {
                const float  d = Dbuf[s16 * A_DIM + i];                    // broadcast
                const float4 a = *(const float4*)&As[i * LDSROW + 4 * fc]; // row-contig
                p.x += d * a.x; p.y += d * a.y; p.z += d * a.z; p.w += d * a.w;
            }
            const float4 dj = *(const float4*)&Dbuf[s16 * A_DIM + 4 * fc];
            Par[s16 * 33 + fc] = p.x * dj.x + p.y * dj.y + p.z * dj.z + p.w * dj.w;
        }
        __syncthreads();
        if (tid < m) {
            const int n = idxL[c0 + tid];
            float q = 0.f;
            #pragma unroll
            for (int j = 0; j < 32; ++j) q += Par[tid * 33 + j];
            score[n * K_CL + (bid & 3)] = q + ld;
        }
        __syncthreads();
    }
}

// ---------------------------------------------------------------------------
// Kernel 3 (unchanged round-11): 256 blocks x 8 samples, W transposed in LDS,
// per-block loss accumulation.
// ---------------------------------------------------------------------------
__global__ __launch_bounds__(256) void k_out(
    const float* __restrict__ features, const float* __restrict__ weight,
    const float* __restrict__ bias, const int* __restrict__ labels,
    const float* __restrict__ score, const float* __restrict__ gdiag,
    const float* __restrict__ gcol, const float* __restrict__ ratio_p,
    float* __restrict__ y, float* __restrict__ loss)
{
    __shared__ float Wt[A_DIM * WTPAD];     // 51.7 KB transposed W
    __shared__ float bs[C_CLS];
    __shared__ __align__(16) float xs[2][A_DIM];
    __shared__ float red[2][2], red2[2][2], acl_s[2], lsum;

    const int tid  = threadIdx.x;
    const int half = tid >> 7;              // which sample of the pair
    const int t    = tid & 127;

    for (int u = tid; u < C_CLS * 32; u += 256) {
        const int c = u >> 5, j4 = u & 31;
        const float4 w = ((const float4*)weight)[u];
        Wt[(4 * j4 + 0) * WTPAD + c] = w.x;
        Wt[(4 * j4 + 1) * WTPAD + c] = w.y;
        Wt[(4 * j4 + 2) * WTPAD + c] = w.z;
        Wt[(4 * j4 + 3) * WTPAD + c] = w.w;
    }
    if (tid < C_CLS) bs[tid] = bias[tid];
    if (tid == 0) lsum = 0.f;
    __syncthreads();

    const float ratio = *ratio_p;

    for (int p = 0; p < SPB; p += 2) {
        const int n = blockIdx.x * SPB + p + half;
        if (t < 32) ((float4*)xs[half])[t] = ((const float4*)features)[n * 32 + t];
        __syncthreads();

        const int cl = labels[n];
        float s0 = score[n * 4 + 0], s1 = score[n * 4 + 1];
        float s2 = score[n * 4 + 2], s3 = score[n * 4 + 3];
        int ks = 0; float bsv = s0;              // strict <: first-min == jnp first-max
        if (s1 < bsv) { bsv = s1; ks = 1; }
        if (s2 < bsv) { bsv = s2; ks = 2; }
        if (s3 < bsv) { bsv = s3; ks = 3; }

        const int base = (cl * 4 + ks) * C_CLS;
        const float gll = gdiag[base + cl];
        float aug = -INFINITY;
        if (t < C_CLS) {
            float acc = bs[t];
            #pragma unroll 4
            for (int j = 0; j < A_DIM; ++j)
                acc += xs[half][j] * Wt[j * WTPAD + t];   // broadcast x conflict-free
            y[(size_t)n * C_CLS + t] = acc;
            aug = acc + 0.5f * ratio * (gdiag[base + t] - 2.0f * gcol[base + t] + gll);
        }

        float m = aug;
        #pragma unroll
        for (int off = 32; off; off >>= 1) m = fmaxf(m, __shfl_xor(m, off, 64));
        if ((t & 63) == 0) red[half][t >> 6] = m;
        __syncthreads();
        m = fmaxf(red[half][0], red[half][1]);

        float e = (t < C_CLS) ? expf(aug - m) : 0.0f;
        #pragma unroll
        for (int off = 32; off; off >>= 1) e += __shfl_xor(e, off, 64);
        if ((t & 63) == 0) red2[half][t >> 6] = e;
        if (t == cl) acl_s[half] = aug;
        __syncthreads();

        if (t == 0) {
            float lp = acl_s[half] - m - logf(red2[half][0] + red2[half][1]);
            atomicAdd(&lsum, -lp);
        }
        __syncthreads();    // protect xs/red before next pair
    }
    if (tid == 0) atomicAdd(loss, lsum * (1.0f / (float)N_S));
}

// ---------------------------------------------------------------------------
extern "C" void kernel_launch(void* const* d_in, const int* in_sizes, int n_in,
                              void* d_out, int out_size, void* d_ws, size_t ws_size,
                              hipStream_t stream) {
    const float* features = (const float*)d_in[0];
    const float* weight   = (const float*)d_in[1];
    const float* bias     = (const float*)d_in[2];
    // d_in[3] = pi : unused (q is one-hot for any pi > 0; argmax unaffected)
    const float* mu       = (const float*)d_in[4];
    const float* sigma    = (const float*)d_in[5];
    const int*   labels   = (const int*)d_in[6];
    const float* ratio    = (const float*)d_in[7];

    float* out   = (float*)d_out;   // [0] = loss, [1..204800] = y
    float* yout  = out + 1;
    float* score = (float*)d_ws;                  // 8192 f32
    float* gdiag = score + N_S * K_CL;            // 40000 f32
    float* gcol  = gdiag + C_CLS * K_CL * C_CLS;  // 40000 f32

    hipMemsetAsync(d_out, 0, sizeof(float), stream);   // zero the loss accumulator

    k_fused<<<dim3(C_CLS * K_CL), dim3(512), 0, stream>>>(sigma, mu, features, labels,
                                                          weight, score, gdiag, gcol);
    k_out  <<<dim3(N_S / SPB),    dim3(256), 0, stream>>>(features, weight, bias, labels,
                                                          score, gdiag, gcol, ratio, yout, out);
}